// Round 10
// baseline (3189.049 us; speedup 1.0000x reference)
//
#include <hip/hip_runtime.h>
#include <hip/hip_bf16.h>
#include <hip/hip_cooperative_groups.h>

namespace cg = cooperative_groups;

typedef __hip_bfloat16 bf16;
typedef __attribute__((ext_vector_type(8))) short bf16x8;
typedef __attribute__((ext_vector_type(4))) float f32x4;

#define NSTEP 6

static __device__ __forceinline__ float b2f(bf16 v) { return __bfloat162float(v); }

static __device__ __forceinline__ float ldp(const void* p, int i, int md) {
    return md ? ((const float*)p)[i] : b2f(((const bf16*)p)[i]);
}
static __device__ __forceinline__ float finz(float v) {
    return (v == v && v * 0.0f == 0.0f) ? v : 0.0f;
}
static __device__ __forceinline__ unsigned short f2bfu(float v) {
    bf16 h = __float2bfloat16(v);
    return *(unsigned short*)&h;
}
static __device__ __forceinline__ float su2f(short s) {
    return __uint_as_float(((unsigned)(unsigned short)s) << 16);
}
static __device__ __forceinline__ void ld_bf8(const bf16* p, float* f) {
    union { uint4 u; unsigned short s[8]; } r;
    r.u = *(const uint4*)p;
#pragma unroll
    for (int j = 0; j < 8; ++j) f[j] = __uint_as_float(((unsigned)r.s[j]) << 16);
}
static __device__ __forceinline__ void ldp8(const void* p, int i, int md, float* f) {
    if (md) {
        const float* fp = (const float*)p + i;
        float4 a = *(const float4*)fp, b = *(const float4*)(fp + 4);
        f[0]=a.x; f[1]=a.y; f[2]=a.z; f[3]=a.w; f[4]=b.x; f[5]=b.y; f[6]=b.z; f[7]=b.w;
    } else {
        ld_bf8((const bf16*)p + i, f);
    }
}
static __device__ __forceinline__ uint4 pk_bf8(const float* f) {
    union { uint4 u; unsigned short s[8]; } r;
#pragma unroll
    for (int j = 0; j < 8; ++j) r.s[j] = f2bfu(f[j]);
    return r.u;
}

// ---------------- setup kernels ----------------

__global__ void k_detect(const uint4* __restrict__ m4,
                         const uint4* __restrict__ x4,
                         int* __restrict__ flags, float* __restrict__ accv) {
    __shared__ int s3f, sup, slo, sf32;
    int t = threadIdx.x;
    if (t == 0) { s3f = 0; sup = 0; slo = 0; sf32 = 0; }
    if (t < 96) accv[t] = 0.f;
    __syncthreads();
    int l3f = 0, lup = 0, llo = 0, lf = 0;
    for (int i = t; i < 3072; i += 256) {
        uint4 v = m4[i];
        const unsigned* d = (const unsigned*)&v;
#pragma unroll
        for (int j = 0; j < 4; ++j) {
            unsigned w = d[j];
            unsigned x3f = w ^ 0x3F3F3F3Fu;
            if ((x3f - 0x01010101u) & ~x3f & 0x80808080u) l3f = 1;
            if (w & 0xFFFFFF00u) lup = 1;
            if (w & 0x0000FFFFu) llo = 1;
        }
    }
    for (int i = t; i < 4096; i += 256) {
        uint4 v = x4[i];
        const unsigned* d = (const unsigned*)&v;
#pragma unroll
        for (int j = 0; j < 4; ++j) {
            unsigned bb = (d[j] >> 8) & 0x7Fu;
            if (bb > 0x48u) lf = 1;
        }
    }
    if (l3f) atomicOr(&s3f, 1);
    if (lup) atomicOr(&sup, 1);
    if (llo) atomicOr(&slo, 1);
    if (lf)  atomicOr(&sf32, 1);
    __syncthreads();
    if (t == 0) {
        int mode;
        if (!s3f && !sup) mode = 0;
        else if (!s3f)    mode = 1;
        else if (slo)     mode = 2;
        else              mode = 3;
        flags[0] = mode;
        flags[1] = sf32;
    }
}

__global__ void k_cast(const void* __restrict__ in, float* __restrict__ out,
                       const int* __restrict__ mflags, int n8) {
    int md = mflags[1];
    int i = blockIdx.x * 256 + threadIdx.x;
    if (i < n8) {
        float f[8];
        ldp8(in, i * 8, md, f);
#pragma unroll
        for (int j = 0; j < 8; ++j) f[j] = finz(f[j]);
        *(float4*)&out[i * 8]     = make_float4(f[0], f[1], f[2], f[3]);
        *(float4*)&out[i * 8 + 4] = make_float4(f[4], f[5], f[6], f[7]);
    }
}

__global__ void k_transpose(const void* __restrict__ in, float* __restrict__ out,
                            const int* __restrict__ mflags, int R, int K) {
    int md = mflags[1];
    int i = blockIdx.x * 256 + threadIdx.x;
    if (i < R * K) {
        int k = i / R, r = i % R;
        out[i] = ldp(in, r * K + k, md);
    }
}

__global__ void k_pack_bt1(const void* __restrict__ p0, const void* __restrict__ p1,
                           short* __restrict__ out, const int* __restrict__ mflags) {
    int md = mflags[1];
    int i = blockIdx.x * 256 + threadIdx.x;
    if (i < 128 * 576) {
        int o = i / 576, k = i % 576;
        int kk = k >> 6, ii = k & 63;
        float v = (o < 64) ? ldp(p0, o * 576 + ii * 9 + kk, md)
                           : ldp(p1, (o - 64) * 576 + ii * 9 + kk, md);
        out[i] = (short)f2bfu(v);
    }
}

__global__ void k_pack_all(const void* __restrict__ fc0w, const void* __restrict__ fc1w,
                           const void* __restrict__ qkvw, const void* __restrict__ outw,
                           const void* __restrict__ ff1w, const void* __restrict__ ff2w,
                           short* __restrict__ out, const int* __restrict__ mflags) {
    int md = mflags[1];
    int i = blockIdx.x * 256 + threadIdx.x;
    if (i < 57344) {
        float v;
        if (i < 24576)      v = ldp(fc0w, i, md);
        else if (i < 32768) v = ldp(fc1w, i - 24576, md);
        else if (i < 45056) v = ldp(qkvw, i - 32768, md);
        else if (i < 49152) v = ldp(outw, i - 45056, md);
        else if (i < 53248) v = ldp(ff1w, i - 49152, md);
        else                v = ldp(ff2w, i - 53248, md);
        out[i] = (short)f2bfu(v);
    }
}

// ================= fused cooperative kernel: 256 blocks x 1024 threads ======
// Each 512-thread half-block owns one B*H row. Per-row LDS: R0 28512 + R1 44288.
// Block total 146368 B -> 1 block/CU guaranteed (16 waves/CU).
__global__ __launch_bounds__(1024, 4) void kfused(
    float* __restrict__ xst, bf16* __restrict__ qkvb,
    const short* __restrict__ bt1, const short* __restrict__ fc0s,
    const short* __restrict__ fc1s, const short* __restrict__ qkvs,
    const short* __restrict__ outs, const short* __restrict__ ff1s,
    const short* __restrict__ ff2s,
    const void* __restrict__ p0b, const void* __restrict__ p1b,
    const void* __restrict__ fc0b, const void* __restrict__ n0w,
    const void* __restrict__ n0b, const void* __restrict__ ln1w,
    const void* __restrict__ ln1b, const void* __restrict__ outb,
    const void* __restrict__ ln2w, const void* __restrict__ ln2b,
    const void* __restrict__ ff1b, const void* __restrict__ ff2b,
    const void* __restrict__ mraw, const int* __restrict__ mflags,
    float* __restrict__ accv, void* __restrict__ dout)
{
    __shared__ __align__(16) char R0a[2][28512];
    __shared__ __align__(16) char R1a[2][44288];
    __shared__ float c0s[2][64];
    __shared__ float red[2][32];

    cg::grid_group grid = cg::this_grid();

    int md = mflags[1];
    int mmode = mflags[0];
    int half = threadIdx.x >> 9;
    int tt = threadIdx.x & 511;
    int bh = (blockIdx.x << 1) | half;
    int b = bh >> 6, h = bh & 63;
    char* R0 = R0a[half];
    char* R1 = R1a[half];
    float* c0h = c0s[half];
    float* redh = red[half];

    int og = __builtin_amdgcn_readfirstlane(tt >> 6);   // wave-in-half 0..7
    int l = tt & 63, nl = l & 15, qd = l >> 4;

    for (int s = 0; s < NSTEP; ++s) {
        // ================= Phase A: perceive (conv + fc0 on MFMA) =============
        {
            short* xpad = (short*)R0;              // [3][66][72]
            short* P    = (short*)R1;              // [64][200]
            short* hdL  = (short*)R0;              // [64][136], after xpad dead

            for (int e = tt; e < 1536; e += 512) {
                int c8 = e & 7, w = (e >> 3) & 63, r = e >> 9;
                int hr = h - 1 + r; hr = hr < 0 ? -hr : (hr > 63 ? 126 - hr : hr);
                const float* src = xst + ((((b << 6) + hr) << 6) | w) * 64 + c8 * 8;
                float f[8];
                float4 v0 = *(const float4*)src, v1 = *(const float4*)(src + 4);
                f[0]=v0.x; f[1]=v0.y; f[2]=v0.z; f[3]=v0.w; f[4]=v1.x; f[5]=v1.y; f[6]=v1.z; f[7]=v1.w;
                uint4 pv = pk_bf8(f);
                *(uint4*)&xpad[((r * 66) + w + 1) * 72 + c8 * 8] = pv;
                if (r == 1) *(uint4*)&P[w * 200 + c8 * 8] = pv;
            }
            if (tt < 48) {
                int c8 = tt & 7, side = (tt >> 3) & 1, r = tt >> 4;
                int hr = h - 1 + r; hr = hr < 0 ? -hr : (hr > 63 ? 126 - hr : hr);
                int wsrc = side ? 62 : 1, wp = side ? 65 : 0;
                const float* src = xst + ((((b << 6) + hr) << 6) | wsrc) * 64 + c8 * 8;
                float f[8];
                float4 v0 = *(const float4*)src, v1 = *(const float4*)(src + 4);
                f[0]=v0.x; f[1]=v0.y; f[2]=v0.z; f[3]=v0.w; f[4]=v1.x; f[5]=v1.y; f[6]=v1.z; f[7]=v1.w;
                *(uint4*)&xpad[((r * 66) + wp) * 72 + c8 * 8] = pk_bf8(f);
            }
            __syncthreads();

            int mt0 = (og & 1) * 2;
            int nt0 = (og >> 1) * 2;
            int o0 = nt0 * 16 + nl, o1 = o0 + 16;

            f32x4 acc[2][2];
#pragma unroll
            for (int i = 0; i < 2; ++i)
#pragma unroll
                for (int j = 0; j < 2; ++j) acc[i][j] = (f32x4){0.f, 0.f, 0.f, 0.f};

            for (int kt = 0; kt < 18; ++kt) {
                int kk = kt >> 1, c0 = (kt & 1) << 5;
                int r = kk / 3, cxi = kk - r * 3;
                bf16x8 b0 = *(const bf16x8*)(bt1 + o0 * 576 + kt * 32 + qd * 8);
                bf16x8 b1 = *(const bf16x8*)(bt1 + o1 * 576 + kt * 32 + qd * 8);
                bf16x8 a0 = *(const bf16x8*)&xpad[((r * 66) + mt0 * 16 + nl + cxi) * 72 + c0 + qd * 8];
                bf16x8 a1 = *(const bf16x8*)&xpad[((r * 66) + mt0 * 16 + 16 + nl + cxi) * 72 + c0 + qd * 8];
                acc[0][0] = __builtin_amdgcn_mfma_f32_16x16x32_bf16(a0, b0, acc[0][0], 0, 0, 0);
                acc[0][1] = __builtin_amdgcn_mfma_f32_16x16x32_bf16(a0, b1, acc[0][1], 0, 0, 0);
                acc[1][0] = __builtin_amdgcn_mfma_f32_16x16x32_bf16(a1, b0, acc[1][0], 0, 0, 0);
                acc[1][1] = __builtin_amdgcn_mfma_f32_16x16x32_bf16(a1, b1, acc[1][1], 0, 0, 0);
            }
            {
                float bias0 = (o0 < 64) ? ldp(p0b, o0, md) : ldp(p1b, o0 - 64, md);
                float bias1 = (o1 < 64) ? ldp(p0b, o1, md) : ldp(p1b, o1 - 64, md);
#pragma unroll
                for (int i = 0; i < 2; ++i)
#pragma unroll
                    for (int j = 0; j < 2; ++j) {
                        int oo = j ? o1 : o0;
                        float bb = j ? bias1 : bias0;
#pragma unroll
                        for (int r2 = 0; r2 < 4; ++r2) {
                            int m = (mt0 + i) * 16 + qd * 4 + r2;
                            P[m * 200 + 64 + oo] = (short)f2bfu(acc[i][j][r2] + bb);
                        }
                    }
            }
            __syncthreads();   // xpad dead

#pragma unroll
            for (int i = 0; i < 2; ++i)
#pragma unroll
                for (int j = 0; j < 2; ++j) acc[i][j] = (f32x4){0.f, 0.f, 0.f, 0.f};
            for (int kt = 0; kt < 6; ++kt) {
                bf16x8 b0 = *(const bf16x8*)(fc0s + o0 * 192 + kt * 32 + qd * 8);
                bf16x8 b1 = *(const bf16x8*)(fc0s + o1 * 192 + kt * 32 + qd * 8);
                bf16x8 a0 = *(const bf16x8*)&P[(mt0 * 16 + nl) * 200 + kt * 32 + qd * 8];
                bf16x8 a1 = *(const bf16x8*)&P[(mt0 * 16 + 16 + nl) * 200 + kt * 32 + qd * 8];
                acc[0][0] = __builtin_amdgcn_mfma_f32_16x16x32_bf16(a0, b0, acc[0][0], 0, 0, 0);
                acc[0][1] = __builtin_amdgcn_mfma_f32_16x16x32_bf16(a0, b1, acc[0][1], 0, 0, 0);
                acc[1][0] = __builtin_amdgcn_mfma_f32_16x16x32_bf16(a1, b0, acc[1][0], 0, 0, 0);
                acc[1][1] = __builtin_amdgcn_mfma_f32_16x16x32_bf16(a1, b1, acc[1][1], 0, 0, 0);
            }
            float lsum = 0.f, lsq = 0.f;
            {
                float fb0 = ldp(fc0b, o0, md), fb1 = ldp(fc0b, o1, md);
#pragma unroll
                for (int i = 0; i < 2; ++i)
#pragma unroll
                    for (int j = 0; j < 2; ++j) {
                        int oo = j ? o1 : o0;
                        float bb = j ? fb1 : fb0;
#pragma unroll
                        for (int r2 = 0; r2 < 4; ++r2) {
                            int m = (mt0 + i) * 16 + qd * 4 + r2;
                            float v = fmaxf(acc[i][j][r2] + bb, 0.f);
                            unsigned short hu = f2bfu(v);
                            hdL[m * 136 + oo] = (short)hu;
                            float vr = __uint_as_float(((unsigned)hu) << 16);
                            lsum += vr; lsq += vr * vr;
                        }
                    }
            }
#pragma unroll
            for (int off = 32; off > 0; off >>= 1) {
                lsum += __shfl_down(lsum, off, 64);
                lsq  += __shfl_down(lsq,  off, 64);
            }
            if (l == 0) { redh[og] = lsum; redh[16 + og] = lsq; }
            __syncthreads();
            if (tt == 0) {
                float a = 0.f, s2 = 0.f;
#pragma unroll
                for (int w = 0; w < 8; ++w) { a += redh[w]; s2 += redh[16 + w]; }
                atomicAdd(&accv[s * 16 + b * 2],     a);
                atomicAdd(&accv[s * 16 + b * 2 + 1], s2);
            }
        }
        grid.sync();

        // ============ Phase B: LN0 + fc1 (MFMA) + mask/residual + ln1 + qkv ===
        {
            short* hdL    = (short*)R0;            // [64][136]
            short* hdnb   = (short*)R1;            // [64][136]
            float* xrowf  = (float*)(R1 + 17408);  // [64][68]
            short* ysb    = (short*)(R1 + 34816);  // [64][72]
            short* qstage = (short*)R1;            // [64][200] after hdnb/xrowf dead

            const float invN = 1.f / 524288.f;
            float mean = accv[s * 16 + b * 2] * invN;
            float var  = accv[s * 16 + b * 2 + 1] * invN - mean * mean;
            float rstd = rsqrtf(fmaxf(var, 0.f) + 1e-5f);

            for (int e = tt; e < 1024; e += 512) {
                int pos = e >> 4, j8 = (e & 15) * 8;
                float hv[8], wv[8], bv[8], ov[8];
                ld_bf8((const bf16*)&hdL[pos * 136 + j8], hv);
                int ni = (h * 64 + pos) * 128 + j8;
                ldp8(n0w, ni, md, wv);
                ldp8(n0b, ni, md, bv);
#pragma unroll
                for (int j = 0; j < 8; ++j) ov[j] = (hv[j] - mean) * rstd * wv[j] + bv[j];
                *(uint4*)&hdnb[pos * 136 + j8] = pk_bf8(ov);
            }
            {
                int pos = tt >> 3, c8 = (tt & 7) * 8;
                const float* src = xst + ((bh << 6) + pos) * 64 + c8;
                *(float4*)&xrowf[pos * 68 + c8]     = *(const float4*)src;
                *(float4*)&xrowf[pos * 68 + c8 + 4] = *(const float4*)(src + 4);
            }
            __syncthreads();

            int mt = og & 3;
            int nt0 = (og >> 2) * 2;
            int o0 = nt0 * 16 + nl, o1 = o0 + 16;
            f32x4 f0 = (f32x4){0.f,0.f,0.f,0.f}, f1 = (f32x4){0.f,0.f,0.f,0.f};
#pragma unroll
            for (int kt = 0; kt < 4; ++kt) {
                bf16x8 av = *(const bf16x8*)&hdnb[(mt * 16 + nl) * 136 + kt * 32 + qd * 8];
                bf16x8 b0 = *(const bf16x8*)(fc1s + o0 * 128 + kt * 32 + qd * 8);
                bf16x8 b1 = *(const bf16x8*)(fc1s + o1 * 128 + kt * 32 + qd * 8);
                f0 = __builtin_amdgcn_mfma_f32_16x16x32_bf16(av, b0, f0, 0, 0, 0);
                f1 = __builtin_amdgcn_mfma_f32_16x16x32_bf16(av, b1, f1, 0, 0, 0);
            }
            int mk[4];
#pragma unroll
            for (int r2 = 0; r2 < 4; ++r2) {
                int m_ = mt * 16 + qd * 4 + r2;
                int midx = ((s * 8 + b) * 64 + h) * 64 + m_;
                if (mmode == 0)      mk[r2] = ((const int*)mraw)[midx] != 0;
                else if (mmode == 1) mk[r2] = ((const unsigned char*)mraw)[midx] != 0;
                else if (mmode == 2) mk[r2] = ((const unsigned short*)mraw)[midx] != 0;
                else                 mk[r2] = ((const float*)mraw)[midx] != 0.0f;
            }
#pragma unroll
            for (int j = 0; j < 2; ++j)
#pragma unroll
                for (int r2 = 0; r2 < 4; ++r2) {
                    int m_ = mt * 16 + qd * 4 + r2;
                    int n_ = j ? o1 : o0;
                    float xv = xrowf[m_ * 68 + n_];
                    if (n_ == 0) c0h[m_] = xv;
                    float dx = j ? f1[r2] : f0[r2];
                    xrowf[m_ * 68 + n_] = finz(mk[r2] ? (xv + dx) : xv);
                }
            __syncthreads();

            {
                int pos = tt >> 3, c8 = (tt & 7) * 8;
                float v[8];
#pragma unroll
                for (int ci = 0; ci < 8; ++ci) v[ci] = xrowf[pos * 68 + c8 + ci];
                float* dst = xst + ((bh << 6) + pos) * 64 + c8;
                *(float4*)dst       = make_float4(v[0], v[1], v[2], v[3]);
                *(float4*)(dst + 4) = make_float4(v[4], v[5], v[6], v[7]);
                float ls = 0.f, lq = 0.f;
#pragma unroll
                for (int ci = 0; ci < 8; ++ci) { ls += v[ci]; lq += v[ci] * v[ci]; }
#pragma unroll
                for (int off = 1; off < 8; off <<= 1) {
                    ls += __shfl_xor(ls, off, 64);
                    lq += __shfl_xor(lq, off, 64);
                }
                float mu = ls * (1.f / 64.f);
                float vr = lq * (1.f / 64.f) - mu * mu;
                float rs = rsqrtf(fmaxf(vr, 0.f) + 1e-5f);
                float wv[8], bv[8], yv[8];
                ldp8(ln1w, c8, md, wv);
                ldp8(ln1b, c8, md, bv);
#pragma unroll
                for (int ci = 0; ci < 8; ++ci) yv[ci] = (v[ci] - mu) * rs * wv[ci] + bv[ci];
                *(uint4*)&ysb[pos * 72 + c8] = pk_bf8(yv);
            }
            __syncthreads();

            int baseN = (og >> 2) * 6;
            f32x4 qa[6];
#pragma unroll
            for (int n6 = 0; n6 < 6; ++n6) qa[n6] = (f32x4){0.f,0.f,0.f,0.f};
#pragma unroll
            for (int kt = 0; kt < 2; ++kt) {
                bf16x8 av = *(const bf16x8*)&ysb[(mt * 16 + nl) * 72 + kt * 32 + qd * 8];
#pragma unroll
                for (int n6 = 0; n6 < 6; ++n6) {
                    int o = (baseN + n6) * 16 + nl;
                    bf16x8 bq = *(const bf16x8*)(qkvs + o * 64 + kt * 32 + qd * 8);
                    qa[n6] = __builtin_amdgcn_mfma_f32_16x16x32_bf16(av, bq, qa[n6], 0, 0, 0);
                }
            }
#pragma unroll
            for (int n6 = 0; n6 < 6; ++n6)
#pragma unroll
                for (int r2 = 0; r2 < 4; ++r2) {
                    int m_ = mt * 16 + qd * 4 + r2;
                    int o = (baseN + n6) * 16 + nl;
                    qstage[m_ * 200 + o] = (short)f2bfu(qa[n6][r2]);
                }
            __syncthreads();
#pragma unroll
            for (int j = 0; j < 3; ++j) {
                int flat = tt * 3 + j;
                int row = flat / 24, c16 = (flat % 24) * 8;
                *(uint4*)&qkvb[((bh << 6) + row) * 192 + c16] = *(uint4*)&qstage[row * 200 + c16];
            }
        }
        __threadfence();
        grid.sync();

        // ============ Phase C: local attention + out-proj/MLP (MFMA) ==========
        {
            short* kvb = (short*)R1;               // bf16 [64][199]
            short* Ao  = (short*)R1;               // [64][72] after kv dead
            float* ts  = (float*)(R1 + 9216);      // [64][65]
            short* ysC = (short*)(R1 + 25856);     // [64][72]
            short* hsC = (short*)(R1 + 35072);     // [64][72]

            if (tt < 192) {
                int c = tt & 63, r = tt >> 6;
                kvb[c * 199 + r * 66]      = 0;
                kvb[c * 199 + r * 66 + 65] = 0;
            }
            for (int e = tt; e < 1536; e += 512) {
                int c8 = (e & 7) * 8, w = (e >> 3) & 63, r = e >> 9;
                int hr = h - 1 + r;
                union { uint4 u; short s[8]; } rv;
                if (hr >= 0 && hr <= 63) {
                    rv.u = *(const uint4*)(qkvb + ((b * 64 + hr) * 64 + w) * 192 + 64 + c8);
                } else {
                    rv.u = make_uint4(0, 0, 0, 0);
                }
#pragma unroll
                for (int j = 0; j < 8; ++j) kvb[(c8 + j) * 199 + r * 66 + w + 1] = rv.s[j];
            }
            __syncthreads();

            int head = __builtin_amdgcn_readfirstlane((tt >> 6) & 3);
            int pos  = tt & 63;
            float q[16];
            {
                const bf16* qr = qkvb + (((b * 64 + h) * 64) + pos) * 192 + head * 16;
                ld_bf8(qr, q); ld_bf8(qr + 8, q + 8);
            }
            float a[9];
#pragma unroll
            for (int r = 0; r < 3; ++r)
#pragma unroll
                for (int cxi = 0; cxi < 3; ++cxi) {
                    float dot = 0.f;
#pragma unroll
                    for (int d = 0; d < 16; ++d)
                        dot = fmaf(q[d], su2f(kvb[(head * 16 + d) * 199 + r * 66 + pos + cxi]), dot);
                    a[r * 3 + cxi] = dot * 0.25f;
                }
            float mx = a[0];
#pragma unroll
            for (int k = 1; k < 9; ++k) mx = fmaxf(mx, a[k]);
            float ssum = 0.f;
#pragma unroll
            for (int k = 0; k < 9; ++k) { a[k] = __expf(a[k] - mx); ssum += a[k]; }
            float inv = 1.f / ssum;
#pragma unroll
            for (int k = 0; k < 9; ++k) a[k] *= inv;
            __syncthreads();

            for (int e = tt; e < 1536; e += 512) {
                int c8 = (e & 7) * 8, w = (e >> 3) & 63, r = e >> 9;
                int hr = h - 1 + r;
                union { uint4 u; short s[8]; } rv;
                if (hr >= 0 && hr <= 63) {
                    rv.u = *(const uint4*)(qkvb + ((b * 64 + hr) * 64 + w) * 192 + 128 + c8);
                } else {
                    rv.u = make_uint4(0, 0, 0, 0);
                }
#pragma unroll
                for (int j = 0; j < 8; ++j) kvb[(c8 + j) * 199 + r * 66 + w + 1] = rv.s[j];
            }
            __syncthreads();

            float o[16];
#pragma unroll
            for (int d = 0; d < 16; ++d) {
                float ov = 0.f;
#pragma unroll
                for (int r = 0; r < 3; ++r)
#pragma unroll
                    for (int cxi = 0; cxi < 3; ++cxi)
                        ov = fmaf(a[r * 3 + cxi], su2f(kvb[(head * 16 + d) * 199 + r * 66 + pos + cxi]), ov);
                o[d] = ov;
            }
            __syncthreads();   // kv dead

            if (tt < 256) {
                *(uint4*)&Ao[pos * 72 + head * 16]     = pk_bf8(o);
                *(uint4*)&Ao[pos * 72 + head * 16 + 8] = pk_bf8(o + 8);
            }
            __syncthreads();

            int mt = og & 3;
            int nt0 = (og >> 2) * 2;
            int o0 = nt0 * 16 + nl, o1 = o0 + 16;

            {
                f32x4 pa0 = (f32x4){0.f,0.f,0.f,0.f}, pa1 = (f32x4){0.f,0.f,0.f,0.f};
#pragma unroll
                for (int kt = 0; kt < 2; ++kt) {
                    bf16x8 av = *(const bf16x8*)&Ao[(mt * 16 + nl) * 72 + kt * 32 + qd * 8];
                    bf16x8 b0 = *(const bf16x8*)(outs + o0 * 64 + kt * 32 + qd * 8);
                    bf16x8 b1 = *(const bf16x8*)(outs + o1 * 64 + kt * 32 + qd * 8);
                    pa0 = __builtin_amdgcn_mfma_f32_16x16x32_bf16(av, b0, pa0, 0, 0, 0);
                    pa1 = __builtin_amdgcn_mfma_f32_16x16x32_bf16(av, b1, pa1, 0, 0, 0);
                }
                float ob0 = ldp(outb, o0, md), ob1 = ldp(outb, o1, md);
#pragma unroll
                for (int r2 = 0; r2 < 4; ++r2) {
                    int m = mt * 16 + qd * 4 + r2;
                    ts[m * 65 + o0] = pa0[r2] + ob0;
                    ts[m * 65 + o1] = pa1[r2] + ob1;
                }
            }
            __syncthreads();

            int idx = ((bh << 6) + pos) * 64 + (tt >> 6) * 8;
            {
                int cg2 = tt >> 6;
                float4 x0 = *(const float4*)&xst[idx];
                float4 x1 = *(const float4*)&xst[idx + 4];
                float* tp = &ts[pos * 65 + cg2 * 8];
                tp[0] += x0.x; tp[1] += x0.y; tp[2] += x0.z; tp[3] += x0.w;
                tp[4] += x1.x; tp[5] += x1.y; tp[6] += x1.z; tp[7] += x1.w;
            }
            __syncthreads();

            {
                int tok = tt >> 3, j8 = (tt & 7) * 8;
                float v[8];
                float ls = 0.f, lq = 0.f;
#pragma unroll
                for (int ci = 0; ci < 8; ++ci) {
                    v[ci] = ts[tok * 65 + j8 + ci];
                    ls += v[ci]; lq += v[ci] * v[ci];
                }
#pragma unroll
                for (int off = 1; off < 8; off <<= 1) {
                    ls += __shfl_xor(ls, off, 64);
                    lq += __shfl_xor(lq, off, 64);
                }
                float mu = ls * (1.f / 64.f);
                float vr = lq * (1.f / 64.f) - mu * mu;
                float rs = rsqrtf(fmaxf(vr, 0.f) + 1e-5f);
                float wv[8], bv[8], yv[8];
                ldp8(ln2w, j8, md, wv);
                ldp8(ln2b, j8, md, bv);
#pragma unroll
                for (int ci = 0; ci < 8; ++ci) yv[ci] = (v[ci] - mu) * rs * wv[ci] + bv[ci];
                *(uint4*)&ysC[tok * 72 + j8] = pk_bf8(yv);
            }
            __syncthreads();

            {
                f32x4 ma0 = (f32x4){0.f,0.f,0.f,0.f}, ma1 = (f32x4){0.f,0.f,0.f,0.f};
#pragma unroll
                for (int kt = 0; kt < 2; ++kt) {
                    bf16x8 av = *(const bf16x8*)&ysC[(mt * 16 + nl) * 72 + kt * 32 + qd * 8];
                    bf16x8 b0 = *(const bf16x8*)(ff1s + o0 * 64 + kt * 32 + qd * 8);
                    bf16x8 b1 = *(const bf16x8*)(ff1s + o1 * 64 + kt * 32 + qd * 8);
                    ma0 = __builtin_amdgcn_mfma_f32_16x16x32_bf16(av, b0, ma0, 0, 0, 0);
                    ma1 = __builtin_amdgcn_mfma_f32_16x16x32_bf16(av, b1, ma1, 0, 0, 0);
                }
                float f1b0 = ldp(ff1b, o0, md), f1b1 = ldp(ff1b, o1, md);
#pragma unroll
                for (int r2 = 0; r2 < 4; ++r2) {
                    int m = mt * 16 + qd * 4 + r2;
                    float v0 = ma0[r2] + f1b0;
                    float v1 = ma1[r2] + f1b1;
                    hsC[m * 72 + o0] = (short)f2bfu(0.5f * v0 * (1.f + erff(v0 * 0.70710678118654752f)));
                    hsC[m * 72 + o1] = (short)f2bfu(0.5f * v1 * (1.f + erff(v1 * 0.70710678118654752f)));
                }
            }
            __syncthreads();

            {
                f32x4 fa0 = (f32x4){0.f,0.f,0.f,0.f}, fa1 = (f32x4){0.f,0.f,0.f,0.f};
#pragma unroll
                for (int kt = 0; kt < 2; ++kt) {
                    bf16x8 av = *(const bf16x8*)&hsC[(mt * 16 + nl) * 72 + kt * 32 + qd * 8];
                    bf16x8 b0 = *(const bf16x8*)(ff2s + o0 * 64 + kt * 32 + qd * 8);
                    bf16x8 b1 = *(const bf16x8*)(ff2s + o1 * 64 + kt * 32 + qd * 8);
                    fa0 = __builtin_amdgcn_mfma_f32_16x16x32_bf16(av, b0, fa0, 0, 0, 0);
                    fa1 = __builtin_amdgcn_mfma_f32_16x16x32_bf16(av, b1, fa1, 0, 0, 0);
                }
                float f2b0 = ldp(ff2b, o0, md), f2b1 = ldp(ff2b, o1, md);
#pragma unroll
                for (int r2 = 0; r2 < 4; ++r2) {
                    int m = mt * 16 + qd * 4 + r2;
                    ts[m * 65 + o0] += fa0[r2] + f2b0;
                    ts[m * 65 + o1] += fa1[r2] + f2b1;
                }
            }
            __syncthreads();

            {
                int cg2 = tt >> 6;
                float fv[8];
#pragma unroll
                for (int ci = 0; ci < 8; ++ci) {
                    float v = ts[pos * 65 + cg2 * 8 + ci];
                    if (cg2 == 0 && ci == 0) v = c0h[pos];
                    fv[ci] = finz(v);
                }
                *(float4*)&xst[idx]     = make_float4(fv[0], fv[1], fv[2], fv[3]);
                *(float4*)&xst[idx + 4] = make_float4(fv[4], fv[5], fv[6], fv[7]);
                if (s == NSTEP - 1) {
                    if (md) {
                        *(float4*)&((float*)dout)[idx]     = make_float4(fv[0], fv[1], fv[2], fv[3]);
                        *(float4*)&((float*)dout)[idx + 4] = make_float4(fv[4], fv[5], fv[6], fv[7]);
                    } else {
                        *(uint4*)&((bf16*)dout)[idx] = pk_bf8(fv);
                    }
                }
            }
        }
        if (s < NSTEP - 1) {
            __threadfence();
            grid.sync();
        }
    }
}

// ================= fallback path: R8 kernels (proven @701us) ================

__global__ __launch_bounds__(512) void k_perceive(
    const float* __restrict__ xin, const short* __restrict__ bt1,
    const short* __restrict__ fc0s, const void* __restrict__ p0b,
    const void* __restrict__ p1b, const void* __restrict__ fc0b,
    const int* __restrict__ mflags, bf16* __restrict__ hd,
    float* __restrict__ accv, int step)
{
    __shared__ __align__(16) short xpad_s[3 * 66 * 72];
    __shared__ __align__(16) short P_s[64 * 200];
    __shared__ float red[32];
    int md = mflags[1];
    int bh = blockIdx.x;
    int b = bh >> 6, h = bh & 63;
    int t = threadIdx.x;

    for (int e = t; e < 1536; e += 512) {
        int c8 = e & 7, w = (e >> 3) & 63, r = e >> 9;
        int hr = h - 1 + r; hr = hr < 0 ? -hr : (hr > 63 ? 126 - hr : hr);
        const float* src = xin + ((((b << 6) + hr) << 6) | w) * 64 + c8 * 8;
        float f[8];
        float4 v0 = *(const float4*)src, v1 = *(const float4*)(src + 4);
        f[0]=v0.x; f[1]=v0.y; f[2]=v0.z; f[3]=v0.w; f[4]=v1.x; f[5]=v1.y; f[6]=v1.z; f[7]=v1.w;
        uint4 pv = pk_bf8(f);
        *(uint4*)&xpad_s[((r * 66) + w + 1) * 72 + c8 * 8] = pv;
        if (r == 1) *(uint4*)&P_s[w * 200 + c8 * 8] = pv;
    }
    if (t < 48) {
        int c8 = t & 7, side = (t >> 3) & 1, r = t >> 4;
        int hr = h - 1 + r; hr = hr < 0 ? -hr : (hr > 63 ? 126 - hr : hr);
        int wsrc = side ? 62 : 1, wp = side ? 65 : 0;
        const float* src = xin + ((((b << 6) + hr) << 6) | wsrc) * 64 + c8 * 8;
        float f[8];
        float4 v0 = *(const float4*)src, v1 = *(const float4*)(src + 4);
        f[0]=v0.x; f[1]=v0.y; f[2]=v0.z; f[3]=v0.w; f[4]=v1.x; f[5]=v1.y; f[6]=v1.z; f[7]=v1.w;
        *(uint4*)&xpad_s[((r * 66) + wp) * 72 + c8 * 8] = pk_bf8(f);
    }
    __syncthreads();

    int og  = __builtin_amdgcn_readfirstlane(t >> 6);
    int l   = t & 63, nl = l & 15, q = l >> 4;
    int mt0 = (og & 1) * 2;
    int nt0 = (og >> 1) * 2;
    int o0  = nt0 * 16 + nl, o1 = o0 + 16;

    f32x4 acc[2][2];
#pragma unroll
    for (int i = 0; i < 2; ++i)
#pragma unroll
        for (int j = 0; j < 2; ++j) acc[i][j] = (f32x4){0.f, 0.f, 0.f, 0.f};

    for (int kt = 0; kt < 18; ++kt) {
        int kk = kt >> 1, c0 = (kt & 1) << 5;
        int r = kk / 3, cxi = kk - r * 3;
        bf16x8 b0 = *(const bf16x8*)(bt1 + o0 * 576 + kt * 32 + q * 8);
        bf16x8 b1 = *(const bf16x8*)(bt1 + o1 * 576 + kt * 32 + q * 8);
        bf16x8 a0 = *(const bf16x8*)&xpad_s[((r * 66) + mt0 * 16 + nl + cxi) * 72 + c0 + q * 8];
        bf16x8 a1 = *(const bf16x8*)&xpad_s[((r * 66) + mt0 * 16 + 16 + nl + cxi) * 72 + c0 + q * 8];
        acc[0][0] = __builtin_amdgcn_mfma_f32_16x16x32_bf16(a0, b0, acc[0][0], 0, 0, 0);
        acc[0][1] = __builtin_amdgcn_mfma_f32_16x16x32_bf16(a0, b1, acc[0][1], 0, 0, 0);
        acc[1][0] = __builtin_amdgcn_mfma_f32_16x16x32_bf16(a1, b0, acc[1][0], 0, 0, 0);
        acc[1][1] = __builtin_amdgcn_mfma_f32_16x16x32_bf16(a1, b1, acc[1][1], 0, 0, 0);
    }
    {
        float bias0 = (o0 < 64) ? ldp(p0b, o0, md) : ldp(p1b, o0 - 64, md);
        float bias1 = (o1 < 64) ? ldp(p0b, o1, md) : ldp(p1b, o1 - 64, md);
#pragma unroll
        for (int i = 0; i < 2; ++i)
#pragma unroll
            for (int j = 0; j < 2; ++j) {
                int oo = j ? o1 : o0;
                float bb = j ? bias1 : bias0;
#pragma unroll
                for (int r2 = 0; r2 < 4; ++r2) {
                    int m = (mt0 + i) * 16 + q * 4 + r2;
                    P_s[m * 200 + 64 + oo] = (short)f2bfu(acc[i][j][r2] + bb);
                }
            }
    }
    __syncthreads();

#pragma unroll
    for (int i = 0; i < 2; ++i)
#pragma unroll
        for (int j = 0; j < 2; ++j) acc[i][j] = (f32x4){0.f, 0.f, 0.f, 0.f};
    for (int kt = 0; kt < 6; ++kt) {
        bf16x8 b0 = *(const bf16x8*)(fc0s + o0 * 192 + kt * 32 + q * 8);
        bf16x8 b1 = *(const bf16x8*)(fc0s + o1 * 192 + kt * 32 + q * 8);
        bf16x8 a0 = *(const bf16x8*)&P_s[(mt0 * 16 + nl) * 200 + kt * 32 + q * 8];
        bf16x8 a1 = *(const bf16x8*)&P_s[(mt0 * 16 + 16 + nl) * 200 + kt * 32 + q * 8];
        acc[0][0] = __builtin_amdgcn_mfma_f32_16x16x32_bf16(a0, b0, acc[0][0], 0, 0, 0);
        acc[0][1] = __builtin_amdgcn_mfma_f32_16x16x32_bf16(a0, b1, acc[0][1], 0, 0, 0);
        acc[1][0] = __builtin_amdgcn_mfma_f32_16x16x32_bf16(a1, b0, acc[1][0], 0, 0, 0);
        acc[1][1] = __builtin_amdgcn_mfma_f32_16x16x32_bf16(a1, b1, acc[1][1], 0, 0, 0);
    }
    float lsum = 0.f, lsq = 0.f;
    {
        float fb0 = ldp(fc0b, o0, md), fb1 = ldp(fc0b, o1, md);
#pragma unroll
        for (int i = 0; i < 2; ++i)
#pragma unroll
            for (int j = 0; j < 2; ++j) {
                int oo = j ? o1 : o0;
                float bb = j ? fb1 : fb0;
#pragma unroll
                for (int r2 = 0; r2 < 4; ++r2) {
                    int m = (mt0 + i) * 16 + q * 4 + r2;
                    float v = fmaxf(acc[i][j][r2] + bb, 0.f);
                    unsigned short hu = f2bfu(v);
                    hd[((bh << 6) + m) * 128 + oo] = *(bf16*)&hu;
                    float vr = __uint_as_float(((unsigned)hu) << 16);
                    lsum += vr; lsq += vr * vr;
                }
            }
    }
#pragma unroll
    for (int off = 32; off > 0; off >>= 1) {
        lsum += __shfl_down(lsum, off, 64);
        lsq  += __shfl_down(lsq,  off, 64);
    }
    if (l == 0) { red[og] = lsum; red[16 + og] = lsq; }
    __syncthreads();
    if (t == 0) {
        float a = 0.f, s2 = 0.f;
#pragma unroll
        for (int w = 0; w < 8; ++w) { a += red[w]; s2 += red[16 + w]; }
        atomicAdd(&accv[step * 16 + b * 2],     a);
        atomicAdd(&accv[step * 16 + b * 2 + 1], s2);
    }
}

__global__ __launch_bounds__(512) void k_update_qkv(
    float* __restrict__ xio, const bf16* __restrict__ hd,
    const float* __restrict__ fc1t, const void* __restrict__ n0w,
    const void* __restrict__ n0b, const void* __restrict__ mraw,
    const int* __restrict__ mflags, const float* __restrict__ accv,
    float* __restrict__ c0buf, const float* __restrict__ qkvt,
    const void* __restrict__ ln1w, const void* __restrict__ ln1b,
    bf16* __restrict__ qkv, int step)
{
    __shared__ float hdn[64 * 129];
    __shared__ float ys[64 * 65];
    int md = mflags[1];
    int bh = blockIdx.x;
    int b = bh >> 6, h = bh & 63;
    int t = threadIdx.x;
    const float invN = 1.f / 524288.f;
    float mean = accv[step * 16 + b * 2] * invN;
    float var  = accv[step * 16 + b * 2 + 1] * invN - mean * mean;
    float rstd = rsqrtf(fmaxf(var, 0.f) + 1e-5f);

    const bf16* hrow = hd + ((b * 64 + h) * 64) * 128;
    for (int e = t; e < 1024; e += 512) {
        int pos = e >> 4, j8 = (e & 15) * 8;
        float hv[8], wv[8], bv[8];
        ld_bf8(hrow + pos * 128 + j8, hv);
        int ni = (h * 64 + pos) * 128 + j8;
        ldp8(n0w, ni, md, wv);
        ldp8(n0b, ni, md, bv);
#pragma unroll
        for (int j = 0; j < 8; ++j)
            hdn[pos * 129 + j8 + j] = (hv[j] - mean) * rstd * wv[j] + bv[j];
    }
    __syncthreads();

    int cg  = __builtin_amdgcn_readfirstlane(t >> 6);
    int pos = t & 63;
    float acc[8];
#pragma unroll
    for (int ci = 0; ci < 8; ++ci) acc[ci] = 0.f;
    for (int j = 0; j < 128; ++j) {
        float hv = hdn[pos * 129 + j];
        const float* fw = fc1t + j * 64 + cg * 8;
#pragma unroll
        for (int ci = 0; ci < 8; ++ci) acc[ci] = fmaf(fw[ci], hv, acc[ci]);
    }
    int mmode = mflags[0];
    int midx = ((step * 8 + b) * 64 + h) * 64 + pos;
    int m;
    if (mmode == 0)      m = ((const int*)mraw)[midx] != 0;
    else if (mmode == 1) m = ((const unsigned char*)mraw)[midx] != 0;
    else if (mmode == 2) m = ((const unsigned short*)mraw)[midx] != 0;
    else                 m = ((const float*)mraw)[midx] != 0.0f;

    int idx = ((b * 64 + h) * 64 + pos) * 64 + cg * 8;
    float4 x0 = *(const float4*)&xio[idx];
    float4 x1 = *(const float4*)&xio[idx + 4];
    float xv[8] = {x0.x, x0.y, x0.z, x0.w, x1.x, x1.y, x1.z, x1.w};
    if (cg == 0) c0buf[(b * 64 + h) * 64 + pos] = xv[0];
    float xn[8];
#pragma unroll
    for (int ci = 0; ci < 8; ++ci) {
        xn[ci] = finz(m ? (xv[ci] + acc[ci]) : xv[ci]);
        ys[pos * 65 + cg * 8 + ci] = xn[ci];
    }
    *(float4*)&xio[idx]     = make_float4(xn[0], xn[1], xn[2], xn[3]);
    *(float4*)&xio[idx + 4] = make_float4(xn[4], xn[5], xn[6], xn[7]);
    __syncthreads();

    {
        int tok = t >> 3, j8 = (t & 7) * 8;
        float v[8];
        float ls = 0.f, lq = 0.f;
#pragma unroll
        for (int ci = 0; ci < 8; ++ci) {
            v[ci] = ys[tok * 65 + j8 + ci];
            ls += v[ci]; lq += v[ci] * v[ci];
        }
#pragma unroll
        for (int off = 1; off < 8; off <<= 1) {
            ls += __shfl_xor(ls, off, 64);
            lq += __shfl_xor(lq, off, 64);
        }
        float mu = ls * (1.f / 64.f);
        float vr = lq * (1.f / 64.f) - mu * mu;
        float rs = rsqrtf(fmaxf(vr, 0.f) + 1e-5f);
        float wv[8], bv[8];
        ldp8(ln1w, j8, md, wv);
        ldp8(ln1b, j8, md, bv);
#pragma unroll
        for (int ci = 0; ci < 8; ++ci)
            ys[tok * 65 + j8 + ci] = (v[ci] - mu) * rs * wv[ci] + bv[ci];
    }
    __syncthreads();

    float a2[24];
#pragma unroll
    for (int oi = 0; oi < 24; ++oi) a2[oi] = 0.f;
    for (int c = 0; c < 64; ++c) {
        float yv = ys[pos * 65 + c];
        const float* qw = qkvt + c * 192 + cg * 24;
#pragma unroll
        for (int oi = 0; oi < 24; ++oi) a2[oi] = fmaf(qw[oi], yv, a2[oi]);
    }
    union { uint4 u[3]; unsigned short s[24]; } pq;
#pragma unroll
    for (int oi = 0; oi < 24; ++oi) pq.s[oi] = f2bfu(a2[oi]);
    uint4* qrow = (uint4*)(qkv + (((b * 64 + h) * 64) + pos) * 192 + cg * 24);
    qrow[0] = pq.u[0]; qrow[1] = pq.u[1]; qrow[2] = pq.u[2];
}

__global__ __launch_bounds__(512) void k_attn_ff(
    const bf16* __restrict__ qkv, float* __restrict__ xio,
    const float* __restrict__ c0buf, const short* __restrict__ outs,
    const short* __restrict__ ff1s, const short* __restrict__ ff2s,
    const void* __restrict__ outb, const void* __restrict__ ln2w,
    const void* __restrict__ ln2b, const void* __restrict__ ff1b,
    const void* __restrict__ ff2b, const int* __restrict__ mflags,
    void* __restrict__ dout, int write_out)
{
    __shared__ __align__(16) char smraw[50944];
    float* kv = (float*)smraw;
    short* Ao = (short*)smraw;
    float* ts = (float*)(smraw + 9216);
    short* ys = (short*)(smraw + 25856);
    short* hs = (short*)(smraw + 35072);

    int md = mflags[1];
    int bh = blockIdx.x;
    int b = bh >> 6, h = bh & 63;
    int t = threadIdx.x;

    if (t < 192) {
        int c = t & 63, r = t >> 6;
        kv[c * 199 + r * 66]      = 0.f;
        kv[c * 199 + r * 66 + 65] = 0.f;
    }
    for (int e = t; e < 1536; e += 512) {
        int c8 = (e & 7) * 8, w = (e >> 3) & 63, r = e >> 9;
        int hr = h - 1 + r;
        float f[8];
        if (hr >= 0 && hr <= 63) {
            ld_bf8(qkv + ((b * 64 + hr) * 64 + w) * 192 + 64 + c8, f);
        } else {
#pragma unroll
            for (int j = 0; j < 8; ++j) f[j] = 0.f;
        }
#pragma unroll
        for (int j = 0; j < 8; ++j) kv[(c8 + j) * 199 + r * 66 + w + 1] = f[j];
    }
    __syncthreads();

    int head = __builtin_amdgcn_readfirstlane((t >> 6) & 3);
    int pos  = t & 63;
    float q[16];
    {
        const bf16* qr = qkv + (((b * 64 + h) * 64) + pos) * 192 + head * 16;
        ld_bf8(qr, q); ld_bf8(qr + 8, q + 8);
    }

    float a[9];
#pragma unroll
    for (int r = 0; r < 3; ++r)
#pragma unroll
        for (int cxi = 0; cxi < 3; ++cxi) {
            float dot = 0.f;
#pragma unroll
            for (int d = 0; d < 16; ++d)
                dot = fmaf(q[d], kv[(head * 16 + d) * 199 + r * 66 + pos + cxi], dot);
            a[r * 3 + cxi] = dot * 0.25f;
        }
    float mx = a[0];
#pragma unroll
    for (int k = 1; k < 9; ++k) mx = fmaxf(mx, a[k]);
    float ssum = 0.f;
#pragma unroll
    for (int k = 0; k < 9; ++k) { a[k] = __expf(a[k] - mx); ssum += a[k]; }
    float inv = 1.f / ssum;
#pragma unroll
    for (int k = 0; k < 9; ++k) a[k] *= inv;
    __syncthreads();

    for (int e = t; e < 1536; e += 512) {
        int c8 = (e & 7) * 8, w = (e >> 3) & 63, r = e >> 9;
        int hr = h - 1 + r;
        float f[8];
        if (hr >= 0 && hr <= 63) {
            ld_bf8(qkv + ((b * 64 + hr) * 64 + w) * 192 + 128 + c8, f);
        } else {
#pragma unroll
            for (int j = 0; j < 8; ++j) f[j] = 0.f;
        }
#pragma unroll
        for (int j = 0; j < 8; ++j) kv[(c8 + j) * 199 + r * 66 + w + 1] = f[j];
    }
    __syncthreads();

    float o[16];
#pragma unroll
    for (int d = 0; d < 16; ++d) {
        float ov = 0.f;
#pragma unroll
        for (int r = 0; r < 3; ++r)
#pragma unroll
            for (int cxi = 0; cxi < 3; ++cxi)
                ov = fmaf(a[r * 3 + cxi], kv[(head * 16 + d) * 199 + r * 66 + pos + cxi], ov);
        o[d] = ov;
    }
    __syncthreads();

    if (t < 256) {
        *(uint4*)&Ao[pos * 72 + head * 16]     = pk_bf8(o);
        *(uint4*)&Ao[pos * 72 + head * 16 + 8] = pk_bf8(o + 8);
    }
    __syncthreads();

    int og = __builtin_amdgcn_readfirstlane(t >> 6);
    int l = t & 63, nl = l & 15, qd = l >> 4;
    int mt = og & 3;
    int nt0 = (og >> 2) * 2;
    int o0 = nt0 * 16 + nl, o1 = o0 + 16;

    {
        f32x4 pa0 = (f32x4){0.f,0.f,0.f,0.f}, pa1 = (f32x4){0.f,0.f,0.f,0.f};
#pragma unroll
        for (int kt = 0; kt < 2; ++kt) {
            bf16x8 av = *(const bf16x8*)&Ao[(mt * 16 + nl) * 72 + kt * 32 + qd * 8];
            bf16x8 b0 = *(const bf16x8*)(outs + o0 * 64 + kt * 32 + qd * 8);
            bf16x8 b1 = *(const bf16x8*)(outs + o1 * 64 + kt * 32 + qd * 8);
            pa0 = __builtin_amdgcn_mfma_f32_16x16x32_bf16(av, b0, pa0, 0, 0, 0);
            pa1 = __builtin_amdgcn_mfma_f32_16x16x32_bf16(av, b1, pa1, 0, 0, 0);
        }
        float ob0 = ldp(outb, o0, md), ob1 = ldp(outb, o1, md);
#pragma unroll
        for (int r2 = 0; r2 < 4; ++r2) {
            int m = mt * 16 + qd * 4 + r2;
            ts[m * 65 + o0] = pa0[r2] + ob0;
            ts[m * 65 + o1] = pa1[r2] + ob1;
        }
    }
    __syncthreads();

    int idx = ((bh << 6) + pos) * 64 + (t >> 6) * 8;
    {
        int cg2 = t >> 6;
        float4 x0 = *(const float4*)&xio[idx];
        float4 x1 = *(const float4*)&xio[idx + 4];
        float* tp = &ts[pos * 65 + cg2 * 8];
        tp[0] += x0.x; tp[1] += x0.y; tp[2] += x0.z; tp[3] += x0.w;
        tp[4] += x1.x; tp[5] += x1.y; tp[6] += x1.z; tp[7] += x1.w;
    }
    __syncthreads();

    {
        int tok = t >> 3, j8 = (t & 7) * 8;
        float v[8];
        float ls = 0.f, lq = 0.f;
#pragma unroll
        for (int ci = 0; ci < 8; ++ci) {
            v[ci] = ts[tok * 65 + j8 + ci];
            ls += v[ci]; lq += v[ci] * v[ci];
        }
#pragma unroll
        for (int off = 1; off < 8; off <<= 1) {
            ls += __shfl_xor(ls, off, 64);
            lq += __shfl_xor(lq, off, 64);
        }
        float mu = ls * (1.f / 64.f);
        float vr = lq * (1.f / 64.f) - mu * mu;
        float rs = rsqrtf(fmaxf(vr, 0.f) + 1e-5f);
        float wv[8], bv[8], yv[8];
        ldp8(ln2w, j8, md, wv);
        ldp8(ln2b, j8, md, bv);
#pragma unroll
        for (int ci = 0; ci < 8; ++ci) yv[ci] = (v[ci] - mu) * rs * wv[ci] + bv[ci];
        *(uint4*)&ys[tok * 72 + j8] = pk_bf8(yv);
    }
    __syncthreads();

    {
        f32x4 ma0 = (f32x4){0.f,0.f,0.f,0.f}, ma1 = (f32x4){0.f,0.f,0.f,0.f};
#pragma unroll
        for (int kt = 0; kt < 2; ++kt) {
            bf16x8 av = *(const bf16x8*)&ys[(mt * 16 + nl) * 72 + kt * 32 + qd * 8];
            bf16x8 b0 = *(const bf16x8*)(ff1s + o0 * 64 + kt * 32 + qd * 8);
            bf16x8 b1 = *(const bf16x8*)(ff1s + o1 * 64 + kt * 32 + qd * 8);
            ma0 = __builtin_amdgcn_mfma_f32_16x16x32_bf16(av, b0, ma0, 0, 0, 0);
            ma1 = __builtin_amdgcn_mfma_f32_16x16x32_bf16(av, b1, ma1, 0, 0, 0);
        }
        float f1b0 = ldp(ff1b, o0, md), f1b1 = ldp(ff1b, o1, md);
#pragma unroll
        for (int r2 = 0; r2 < 4; ++r2) {
            int m = mt * 16 + qd * 4 + r2;
            float v0 = ma0[r2] + f1b0;
            float v1 = ma1[r2] + f1b1;
            hs[m * 72 + o0] = (short)f2bfu(0.5f * v0 * (1.f + erff(v0 * 0.70710678118654752f)));
            hs[m * 72 + o1] = (short)f2bfu(0.5f * v1 * (1.f + erff(v1 * 0.70710678118654752f)));
        }
    }
    __syncthreads();

    {
        f32x4 fa0 = (f32x4){0.f,0.f,0.f,0.f}, fa1 = (f32x4){0.f,0.f,0.f,0.f};
#pragma unroll
        for (int kt = 0; kt < 2; ++kt) {
            bf16x8 av = *(const bf16x8*)&hs[(mt * 16 + nl) * 72 + kt * 32 + qd * 8];
            bf16x8 b0 = *(const bf16x8*)(ff2s + o0 * 64 + kt * 32 + qd * 8);
            bf16x8 b1 = *(const bf16x8*)(ff2s + o1 * 64 + kt * 32 + qd * 8);
            fa0 = __builtin_amdgcn_mfma_f32_16x16x32_bf16(av, b0, fa0, 0, 0, 0);
            fa1 = __builtin_amdgcn_mfma_f32_16x16x32_bf16(av, b1, fa1, 0, 0, 0);
        }
        float f2b0 = ldp(ff2b, o0, md), f2b1 = ldp(ff2b, o1, md);
#pragma unroll
        for (int r2 = 0; r2 < 4; ++r2) {
            int m = mt * 16 + qd * 4 + r2;
            ts[m * 65 + o0] += fa0[r2] + f2b0;
            ts[m * 65 + o1] += fa1[r2] + f2b1;
        }
    }
    __syncthreads();

    {
        int cg2 = t >> 6;
        float fv[8];
#pragma unroll
        for (int ci = 0; ci < 8; ++ci) {
            float v = ts[pos * 65 + cg2 * 8 + ci];
            if (cg2 == 0 && ci == 0) v = c0buf[(bh << 6) + pos];
            fv[ci] = finz(v);
        }
        *(float4*)&xio[idx]     = make_float4(fv[0], fv[1], fv[2], fv[3]);
        *(float4*)&xio[idx + 4] = make_float4(fv[4], fv[5], fv[6], fv[7]);
        if (write_out) {
            if (md) {
                *(float4*)&((float*)dout)[idx]     = make_float4(fv[0], fv[1], fv[2], fv[3]);
                *(float4*)&((float*)dout)[idx + 4] = make_float4(fv[4], fv[5], fv[6], fv[7]);
            } else {
                *(uint4*)&((bf16*)dout)[idx] = pk_bf8(fv);
            }
        }
    }
}

// ---------------- launch ----------------

extern "C" void kernel_launch(void* const* d_in, const int* in_sizes, int n_in,
                              void* d_out, int out_size, void* d_ws, size_t ws_size,
                              hipStream_t stream) {
    (void)in_sizes; (void)n_in; (void)out_size; (void)ws_size;
    const void* x     = d_in[0];
    const void* masks = d_in[1];
    const void* p0w   = d_in[2];
    const void* p0b   = d_in[3];
    const void* p1w   = d_in[4];
    const void* p1b   = d_in[5];
    const void* fc0w  = d_in[6];
    const void* fc0b  = d_in[7];
    const void* fc1w  = d_in[8];
    const void* n0w   = d_in[9];
    const void* n0b   = d_in[10];
    const void* ln1w  = d_in[11];
    const void* ln1b  = d_in[12];
    const void* qkvw  = d_in[13];
    const void* outw  = d_in[14];
    const void* outb  = d_in[15];
    const void* ln2w  = d_in[16];
    const void* ln2b  = d_in[17];
    const void* ff1w  = d_in[18];
    const void* ff1b  = d_in[19];
    const void* ff2w  = d_in[20];
    const void* ff2b  = d_in[21];

    char* wsb = (char*)d_ws;
    float* xst      = (float*)(wsb + 0);           //  8,388,608 B fp32 state
    bf16*  qkvb     = (bf16*) (wsb + 8388608);     // 12,582,912 B (fallback aliases hd)
    bf16*  hd       = (bf16*) (wsb + 8388608);
    float* c0buf    = (float*)(wsb + 20971520);    //    131,072 B (fallback)
    short* bt1      = (short*)(wsb + 21102592);    //    147,456 B
    short* packbase = (short*)(wsb + 21250048);    //    114,688 B
    float* fc1t     = (float*)(wsb + 21364736);    //     32,768 B (fallback)
    float* qkvt     = (float*)(wsb + 21397504);    //     49,152 B (fallback)
    float* accv     = (float*)(wsb + 21446656);    //        384 B
    int*   mflags   = (int*)  (wsb + 21447040);    //         16 B

    const short* fc0s = packbase;
    const short* fc1s = packbase + 24576;
    const short* qkvs = packbase + 32768;
    const short* outs = packbase + 45056;
    const short* ff1s = packbase + 49152;
    const short* ff2s = packbase + 53248;
    void* dout_p = d_out;

    k_detect<<<1, 256, 0, stream>>>((const uint4*)masks, (const uint4*)x, mflags, accv);
    k_cast<<<1024, 256, 0, stream>>>(x, xst, mflags, 262144);
    k_pack_bt1<<<288, 256, 0, stream>>>(p0w, p1w, bt1, mflags);
    k_pack_all<<<224, 256, 0, stream>>>(fc0w, fc1w, qkvw, outw, ff1w, ff2w,
                                        packbase, mflags);
    k_transpose<<<32, 256, 0, stream>>>(fc1w, fc1t, mflags, 64, 128);
    k_transpose<<<48, 256, 0, stream>>>(qkvw, qkvt, mflags, 192, 64);

    void* kargs[] = {
        (void*)&xst, (void*)&qkvb, (void*)&bt1, (void*)&fc0s, (void*)&fc1s,
        (void*)&qkvs, (void*)&outs, (void*)&ff1s, (void*)&ff2s,
        (void*)&p0b, (void*)&p1b, (void*)&fc0b, (void*)&n0w, (void*)&n0b,
        (void*)&ln1w, (void*)&ln1b, (void*)&outb, (void*)&ln2w, (void*)&ln2b,
        (void*)&ff1b, (void*)&ff2b, (void*)&masks, (void*)&mflags,
        (void*)&accv, (void*)&dout_p
    };
    hipError_t cerr = hipLaunchCooperativeKernel((void*)kfused, dim3(256), dim3(1024),
                                                 kargs, 0, stream);
    if (cerr != hipSuccess) {
        (void)hipGetLastError();   // clear sticky error; use proven 3-kernel path
        for (int s = 0; s < NSTEP; ++s) {
            k_perceive<<<512, 512, 0, stream>>>(xst, bt1, fc0s, p0b, p1b, fc0b,
                                                mflags, hd, accv, s);
            k_update_qkv<<<512, 512, 0, stream>>>(xst, hd, fc1t, n0w, n0b, masks,
                                                  mflags, accv, c0buf, qkvt,
                                                  ln1w, ln1b, qkvb, s);
            k_attn_ff<<<512, 512, 0, stream>>>(qkvb, xst, c0buf, outs, ff1s, ff2s,
                                               outb, ln2w, ln2b, ff1b, ff2b, mflags,
                                               d_out, (s == NSTEP - 1) ? 1 : 0);
        }
    }
}

// Round 11
// 772.520 us; speedup vs baseline: 4.1281x; 4.1281x over previous
//
#include <hip/hip_runtime.h>
#include <hip/hip_bf16.h>

typedef __hip_bfloat16 bf16;
typedef __attribute__((ext_vector_type(8))) short bf16x8;
typedef __attribute__((ext_vector_type(4))) float f32x4;

#define NSTEP 6

static __device__ __forceinline__ float b2f(bf16 v) { return __bfloat162float(v); }

static __device__ __forceinline__ float ldp(const void* p, int i, int md) {
    return md ? ((const float*)p)[i] : b2f(((const bf16*)p)[i]);
}
static __device__ __forceinline__ float finz(float v) {
    return (v == v && v * 0.0f == 0.0f) ? v : 0.0f;
}
static __device__ __forceinline__ unsigned short f2bfu(float v) {
    bf16 h = __float2bfloat16(v);
    return *(unsigned short*)&h;
}
static __device__ __forceinline__ float su2f(short s) {
    return __uint_as_float(((unsigned)(unsigned short)s) << 16);
}
static __device__ __forceinline__ void ld_bf8(const bf16* p, float* f) {
    union { uint4 u; unsigned short s[8]; } r;
    r.u = *(const uint4*)p;
#pragma unroll
    for (int j = 0; j < 8; ++j) f[j] = __uint_as_float(((unsigned)r.s[j]) << 16);
}
static __device__ __forceinline__ void ldp8(const void* p, int i, int md, float* f) {
    if (md) {
        const float* fp = (const float*)p + i;
        float4 a = *(const float4*)fp, b = *(const float4*)(fp + 4);
        f[0]=a.x; f[1]=a.y; f[2]=a.z; f[3]=a.w; f[4]=b.x; f[5]=b.y; f[6]=b.z; f[7]=b.w;
    } else {
        ld_bf8((const bf16*)p + i, f);
    }
}
static __device__ __forceinline__ uint4 pk_bf8(const float* f) {
    union { uint4 u; unsigned short s[8]; } r;
#pragma unroll
    for (int j = 0; j < 8; ++j) r.s[j] = f2bfu(f[j]);
    return r.u;
}

// ---------------- setup kernels ----------------

// flags[0]: masks dtype (0 int32, 1 u8, 2 16-bit, 3 f32); flags[1]: floats bf16/f32
__global__ void k_detect(const uint4* __restrict__ m4,
                         const uint4* __restrict__ x4,
                         int* __restrict__ flags, float* __restrict__ accv) {
    __shared__ int s3f, sup, slo, sf32;
    int t = threadIdx.x;
    if (t == 0) { s3f = 0; sup = 0; slo = 0; sf32 = 0; }
    if (t < 96) accv[t] = 0.f;
    __syncthreads();
    int l3f = 0, lup = 0, llo = 0, lf = 0;
    for (int i = t; i < 3072; i += 256) {
        uint4 v = m4[i];
        const unsigned* d = (const unsigned*)&v;
#pragma unroll
        for (int j = 0; j < 4; ++j) {
            unsigned w = d[j];
            unsigned x3f = w ^ 0x3F3F3F3Fu;
            if ((x3f - 0x01010101u) & ~x3f & 0x80808080u) l3f = 1;
            if (w & 0xFFFFFF00u) lup = 1;
            if (w & 0x0000FFFFu) llo = 1;
        }
    }
    for (int i = t; i < 4096; i += 256) {
        uint4 v = x4[i];
        const unsigned* d = (const unsigned*)&v;
#pragma unroll
        for (int j = 0; j < 4; ++j) {
            unsigned bb = (d[j] >> 8) & 0x7Fu;
            if (bb > 0x48u) lf = 1;
        }
    }
    if (l3f) atomicOr(&s3f, 1);
    if (lup) atomicOr(&sup, 1);
    if (llo) atomicOr(&slo, 1);
    if (lf)  atomicOr(&sf32, 1);
    __syncthreads();
    if (t == 0) {
        int mode;
        if (!s3f && !sup) mode = 0;
        else if (!s3f)    mode = 1;
        else if (slo)     mode = 2;
        else              mode = 3;
        flags[0] = mode;
        flags[1] = sf32;
    }
}

__global__ void k_cast(const void* __restrict__ in, float* __restrict__ out,
                       const int* __restrict__ mflags, int n8) {
    int md = mflags[1];
    int i = blockIdx.x * 256 + threadIdx.x;
    if (i < n8) {
        float f[8];
        ldp8(in, i * 8, md, f);
#pragma unroll
        for (int j = 0; j < 8; ++j) f[j] = finz(f[j]);
        *(float4*)&out[i * 8]     = make_float4(f[0], f[1], f[2], f[3]);
        *(float4*)&out[i * 8 + 4] = make_float4(f[4], f[5], f[6], f[7]);
    }
}

// bt1[o][k] bf16, k = (ky*3+kx)*64 + i
__global__ void k_pack_bt1(const void* __restrict__ p0, const void* __restrict__ p1,
                           short* __restrict__ out, const int* __restrict__ mflags) {
    int md = mflags[1];
    int i = blockIdx.x * 256 + threadIdx.x;
    if (i < 128 * 576) {
        int o = i / 576, k = i % 576;
        int kk = k >> 6, ii = k & 63;
        float v = (o < 64) ? ldp(p0, o * 576 + ii * 9 + kk, md)
                           : ldp(p1, (o - 64) * 576 + ii * 9 + kk, md);
        out[i] = (short)f2bfu(v);
    }
}

__global__ void k_pack_all(const void* __restrict__ fc0w, const void* __restrict__ fc1w,
                           const void* __restrict__ qkvw, const void* __restrict__ outw,
                           const void* __restrict__ ff1w, const void* __restrict__ ff2w,
                           short* __restrict__ out, const int* __restrict__ mflags) {
    int md = mflags[1];
    int i = blockIdx.x * 256 + threadIdx.x;
    if (i < 57344) {
        float v;
        if (i < 24576)      v = ldp(fc0w, i, md);
        else if (i < 32768) v = ldp(fc1w, i - 24576, md);
        else if (i < 45056) v = ldp(qkvw, i - 32768, md);
        else if (i < 49152) v = ldp(outw, i - 45056, md);
        else if (i < 53248) v = ldp(ff1w, i - 49152, md);
        else                v = ldp(ff2w, i - 53248, md);
        out[i] = (short)f2bfu(v);
    }
}

// ---------------- step kernels: grid 512, 512 threads ----------------

// A: conv-as-implicit-GEMM [64x128x576] + fc0 GEMM [64x128x192], MFMA
__global__ __launch_bounds__(512) void k_perceive(
    const float* __restrict__ xin, const short* __restrict__ bt1,
    const short* __restrict__ fc0s, const void* __restrict__ p0b,
    const void* __restrict__ p1b, const void* __restrict__ fc0b,
    const int* __restrict__ mflags, bf16* __restrict__ hd,
    float* __restrict__ accv, int step)
{
    __shared__ __align__(16) short xpad_s[3 * 66 * 72];
    __shared__ __align__(16) short P_s[64 * 200];
    __shared__ float red[32];
    int md = mflags[1];
    int bh = blockIdx.x;
    int b = bh >> 6, h = bh & 63;
    int t = threadIdx.x;

    for (int e = t; e < 1536; e += 512) {
        int c8 = e & 7, w = (e >> 3) & 63, r = e >> 9;
        int hr = h - 1 + r; hr = hr < 0 ? -hr : (hr > 63 ? 126 - hr : hr);
        const float* src = xin + ((((b << 6) + hr) << 6) | w) * 64 + c8 * 8;
        float f[8];
        float4 v0 = *(const float4*)src, v1 = *(const float4*)(src + 4);
        f[0]=v0.x; f[1]=v0.y; f[2]=v0.z; f[3]=v0.w; f[4]=v1.x; f[5]=v1.y; f[6]=v1.z; f[7]=v1.w;
        uint4 pv = pk_bf8(f);
        *(uint4*)&xpad_s[((r * 66) + w + 1) * 72 + c8 * 8] = pv;
        if (r == 1) *(uint4*)&P_s[w * 200 + c8 * 8] = pv;
    }
    if (t < 48) {
        int c8 = t & 7, side = (t >> 3) & 1, r = t >> 4;
        int hr = h - 1 + r; hr = hr < 0 ? -hr : (hr > 63 ? 126 - hr : hr);
        int wsrc = side ? 62 : 1, wp = side ? 65 : 0;
        const float* src = xin + ((((b << 6) + hr) << 6) | wsrc) * 64 + c8 * 8;
        float f[8];
        float4 v0 = *(const float4*)src, v1 = *(const float4*)(src + 4);
        f[0]=v0.x; f[1]=v0.y; f[2]=v0.z; f[3]=v0.w; f[4]=v1.x; f[5]=v1.y; f[6]=v1.z; f[7]=v1.w;
        *(uint4*)&xpad_s[((r * 66) + wp) * 72 + c8 * 8] = pk_bf8(f);
    }
    __syncthreads();

    int og  = __builtin_amdgcn_readfirstlane(t >> 6);
    int l   = t & 63, nl = l & 15, q = l >> 4;
    int mt0 = (og & 1) * 2;
    int nt0 = (og >> 1) * 2;
    int o0  = nt0 * 16 + nl, o1 = o0 + 16;

    f32x4 acc[2][2];
#pragma unroll
    for (int i = 0; i < 2; ++i)
#pragma unroll
        for (int j = 0; j < 2; ++j) acc[i][j] = (f32x4){0.f, 0.f, 0.f, 0.f};

    for (int kt = 0; kt < 18; ++kt) {
        int kk = kt >> 1, c0 = (kt & 1) << 5;
        int r = kk / 3, cxi = kk - r * 3;
        bf16x8 b0 = *(const bf16x8*)(bt1 + o0 * 576 + kt * 32 + q * 8);
        bf16x8 b1 = *(const bf16x8*)(bt1 + o1 * 576 + kt * 32 + q * 8);
        bf16x8 a0 = *(const bf16x8*)&xpad_s[((r * 66) + mt0 * 16 + nl + cxi) * 72 + c0 + q * 8];
        bf16x8 a1 = *(const bf16x8*)&xpad_s[((r * 66) + mt0 * 16 + 16 + nl + cxi) * 72 + c0 + q * 8];
        acc[0][0] = __builtin_amdgcn_mfma_f32_16x16x32_bf16(a0, b0, acc[0][0], 0, 0, 0);
        acc[0][1] = __builtin_amdgcn_mfma_f32_16x16x32_bf16(a0, b1, acc[0][1], 0, 0, 0);
        acc[1][0] = __builtin_amdgcn_mfma_f32_16x16x32_bf16(a1, b0, acc[1][0], 0, 0, 0);
        acc[1][1] = __builtin_amdgcn_mfma_f32_16x16x32_bf16(a1, b1, acc[1][1], 0, 0, 0);
    }
    {
        float bias0 = (o0 < 64) ? ldp(p0b, o0, md) : ldp(p1b, o0 - 64, md);
        float bias1 = (o1 < 64) ? ldp(p0b, o1, md) : ldp(p1b, o1 - 64, md);
#pragma unroll
        for (int i = 0; i < 2; ++i)
#pragma unroll
            for (int j = 0; j < 2; ++j) {
                int oo = j ? o1 : o0;
                float bb = j ? bias1 : bias0;
#pragma unroll
                for (int r2 = 0; r2 < 4; ++r2) {
                    int m = (mt0 + i) * 16 + q * 4 + r2;
                    P_s[m * 200 + 64 + oo] = (short)f2bfu(acc[i][j][r2] + bb);
                }
            }
    }
    __syncthreads();

#pragma unroll
    for (int i = 0; i < 2; ++i)
#pragma unroll
        for (int j = 0; j < 2; ++j) acc[i][j] = (f32x4){0.f, 0.f, 0.f, 0.f};
    for (int kt = 0; kt < 6; ++kt) {
        bf16x8 b0 = *(const bf16x8*)(fc0s + o0 * 192 + kt * 32 + q * 8);
        bf16x8 b1 = *(const bf16x8*)(fc0s + o1 * 192 + kt * 32 + q * 8);
        bf16x8 a0 = *(const bf16x8*)&P_s[(mt0 * 16 + nl) * 200 + kt * 32 + q * 8];
        bf16x8 a1 = *(const bf16x8*)&P_s[(mt0 * 16 + 16 + nl) * 200 + kt * 32 + q * 8];
        acc[0][0] = __builtin_amdgcn_mfma_f32_16x16x32_bf16(a0, b0, acc[0][0], 0, 0, 0);
        acc[0][1] = __builtin_amdgcn_mfma_f32_16x16x32_bf16(a0, b1, acc[0][1], 0, 0, 0);
        acc[1][0] = __builtin_amdgcn_mfma_f32_16x16x32_bf16(a1, b0, acc[1][0], 0, 0, 0);
        acc[1][1] = __builtin_amdgcn_mfma_f32_16x16x32_bf16(a1, b1, acc[1][1], 0, 0, 0);
    }
    float lsum = 0.f, lsq = 0.f;
    {
        float fb0 = ldp(fc0b, o0, md), fb1 = ldp(fc0b, o1, md);
#pragma unroll
        for (int i = 0; i < 2; ++i)
#pragma unroll
            for (int j = 0; j < 2; ++j) {
                int oo = j ? o1 : o0;
                float bb = j ? fb1 : fb0;
#pragma unroll
                for (int r2 = 0; r2 < 4; ++r2) {
                    int m = (mt0 + i) * 16 + q * 4 + r2;
                    float v = fmaxf(acc[i][j][r2] + bb, 0.f);
                    unsigned short hu = f2bfu(v);
                    hd[((bh << 6) + m) * 128 + oo] = *(bf16*)&hu;
                    float vr = __uint_as_float(((unsigned)hu) << 16);
                    lsum += vr; lsq += vr * vr;
                }
            }
    }
#pragma unroll
    for (int off = 32; off > 0; off >>= 1) {
        lsum += __shfl_down(lsum, off, 64);
        lsq  += __shfl_down(lsq,  off, 64);
    }
    if (l == 0) { red[og] = lsum; red[16 + og] = lsq; }
    __syncthreads();
    if (t == 0) {
        float a = 0.f, s2 = 0.f;
#pragma unroll
        for (int w = 0; w < 8; ++w) { a += red[w]; s2 += red[16 + w]; }
        atomicAdd(&accv[step * 16 + b * 2],     a);
        atomicAdd(&accv[step * 16 + b * 2 + 1], s2);
    }
}

// B: LN0 + fc1 (MFMA) + mask/residual + parallel ln1 + qkv (MFMA)
// (logic hardware-validated in R10's fused kernel Phase B)
__global__ __launch_bounds__(512) void k_update_qkv(
    float* __restrict__ xio, const bf16* __restrict__ hd,
    const short* __restrict__ fc1s, const void* __restrict__ n0w,
    const void* __restrict__ n0b, const void* __restrict__ mraw,
    const int* __restrict__ mflags, const float* __restrict__ accv,
    float* __restrict__ c0buf, const short* __restrict__ qkvs,
    const void* __restrict__ ln1w, const void* __restrict__ ln1b,
    bf16* __restrict__ qkv, int step)
{
    // byte map: hdnb bf16[64][136] @0 (17408); xrowf f32[64][68] @17408 (17408);
    // ysb bf16[64][72] @34816 (9216); qstage bf16[64][200] @0 (25600, after
    // hdnb/xrowf dead). total 44032+pad.
    __shared__ __align__(16) char UQ[44288];
    short* hdnb   = (short*)UQ;
    float* xrowf  = (float*)(UQ + 17408);
    short* ysb    = (short*)(UQ + 34816);
    short* qstage = (short*)UQ;

    int md = mflags[1];
    int mmode = mflags[0];
    int bh = blockIdx.x;
    int b = bh >> 6, h = bh & 63;
    int t = threadIdx.x;
    int og = __builtin_amdgcn_readfirstlane(t >> 6);
    int l = t & 63, nl = l & 15, qd = l >> 4;

    const float invN = 1.f / 524288.f;
    float mean = accv[step * 16 + b * 2] * invN;
    float var  = accv[step * 16 + b * 2 + 1] * invN - mean * mean;
    float rstd = rsqrtf(fmaxf(var, 0.f) + 1e-5f);

    const bf16* hrow = hd + ((b * 64 + h) * 64) * 128;
    for (int e = t; e < 1024; e += 512) {
        int pos = e >> 4, j8 = (e & 15) * 8;
        float hv[8], wv[8], bv[8], ov[8];
        ld_bf8(hrow + pos * 128 + j8, hv);
        int ni = (h * 64 + pos) * 128 + j8;
        ldp8(n0w, ni, md, wv);
        ldp8(n0b, ni, md, bv);
#pragma unroll
        for (int j = 0; j < 8; ++j) ov[j] = (hv[j] - mean) * rstd * wv[j] + bv[j];
        *(uint4*)&hdnb[pos * 136 + j8] = pk_bf8(ov);
    }
    {
        int pos = t >> 3, c8 = (t & 7) * 8;
        const float* src = xio + ((bh << 6) + pos) * 64 + c8;
        *(float4*)&xrowf[pos * 68 + c8]     = *(const float4*)src;
        *(float4*)&xrowf[pos * 68 + c8 + 4] = *(const float4*)(src + 4);
    }
    __syncthreads();

    // fc1 MFMA: M=64, N=64, K=128
    int mt = og & 3;
    int nt0 = (og >> 2) * 2;
    int o0 = nt0 * 16 + nl, o1 = o0 + 16;
    f32x4 f0 = (f32x4){0.f,0.f,0.f,0.f}, f1 = (f32x4){0.f,0.f,0.f,0.f};
#pragma unroll
    for (int kt = 0; kt < 4; ++kt) {
        bf16x8 av = *(const bf16x8*)&hdnb[(mt * 16 + nl) * 136 + kt * 32 + qd * 8];
        bf16x8 b0 = *(const bf16x8*)(fc1s + o0 * 128 + kt * 32 + qd * 8);
        bf16x8 b1 = *(const bf16x8*)(fc1s + o1 * 128 + kt * 32 + qd * 8);
        f0 = __builtin_amdgcn_mfma_f32_16x16x32_bf16(av, b0, f0, 0, 0, 0);
        f1 = __builtin_amdgcn_mfma_f32_16x16x32_bf16(av, b1, f1, 0, 0, 0);
    }
    int mk[4];
#pragma unroll
    for (int r2 = 0; r2 < 4; ++r2) {
        int m_ = mt * 16 + qd * 4 + r2;
        int midx = ((step * 8 + b) * 64 + h) * 64 + m_;
        if (mmode == 0)      mk[r2] = ((const int*)mraw)[midx] != 0;
        else if (mmode == 1) mk[r2] = ((const unsigned char*)mraw)[midx] != 0;
        else if (mmode == 2) mk[r2] = ((const unsigned short*)mraw)[midx] != 0;
        else                 mk[r2] = ((const float*)mraw)[midx] != 0.0f;
    }
#pragma unroll
    for (int j = 0; j < 2; ++j)
#pragma unroll
        for (int r2 = 0; r2 < 4; ++r2) {
            int m_ = mt * 16 + qd * 4 + r2;
            int n_ = j ? o1 : o0;
            float xv = xrowf[m_ * 68 + n_];
            if (n_ == 0) c0buf[(bh << 6) + m_] = xv;   // pre-update ch0
            float dx = j ? f1[r2] : f0[r2];
            xrowf[m_ * 68 + n_] = finz(mk[r2] ? (xv + dx) : xv);
        }
    __syncthreads();

    // store xn -> global ; ln1 parallel (8 lanes/token) -> ysb bf16
    {
        int pos = t >> 3, c8 = (t & 7) * 8;
        float v[8];
#pragma unroll
        for (int ci = 0; ci < 8; ++ci) v[ci] = xrowf[pos * 68 + c8 + ci];
        float* dst = xio + ((bh << 6) + pos) * 64 + c8;
        *(float4*)dst       = make_float4(v[0], v[1], v[2], v[3]);
        *(float4*)(dst + 4) = make_float4(v[4], v[5], v[6], v[7]);
        float ls = 0.f, lq = 0.f;
#pragma unroll
        for (int ci = 0; ci < 8; ++ci) { ls += v[ci]; lq += v[ci] * v[ci]; }
#pragma unroll
        for (int off = 1; off < 8; off <<= 1) {
            ls += __shfl_xor(ls, off, 64);
            lq += __shfl_xor(lq, off, 64);
        }
        float mu = ls * (1.f / 64.f);
        float vr = lq * (1.f / 64.f) - mu * mu;
        float rs = rsqrtf(fmaxf(vr, 0.f) + 1e-5f);
        float wv[8], bv[8], yv[8];
        ldp8(ln1w, c8, md, wv);
        ldp8(ln1b, c8, md, bv);
#pragma unroll
        for (int ci = 0; ci < 8; ++ci) yv[ci] = (v[ci] - mu) * rs * wv[ci] + bv[ci];
        *(uint4*)&ysb[pos * 72 + c8] = pk_bf8(yv);
    }
    __syncthreads();

    // qkv MFMA: M=64, N=192, K=64
    int baseN = (og >> 2) * 6;
    f32x4 qa[6];
#pragma unroll
    for (int n6 = 0; n6 < 6; ++n6) qa[n6] = (f32x4){0.f,0.f,0.f,0.f};
#pragma unroll
    for (int kt = 0; kt < 2; ++kt) {
        bf16x8 av = *(const bf16x8*)&ysb[(mt * 16 + nl) * 72 + kt * 32 + qd * 8];
#pragma unroll
        for (int n6 = 0; n6 < 6; ++n6) {
            int o = (baseN + n6) * 16 + nl;
            bf16x8 bq = *(const bf16x8*)(qkvs + o * 64 + kt * 32 + qd * 8);
            qa[n6] = __builtin_amdgcn_mfma_f32_16x16x32_bf16(av, bq, qa[n6], 0, 0, 0);
        }
    }
#pragma unroll
    for (int n6 = 0; n6 < 6; ++n6)
#pragma unroll
        for (int r2 = 0; r2 < 4; ++r2) {
            int m_ = mt * 16 + qd * 4 + r2;
            int o = (baseN + n6) * 16 + nl;
            qstage[m_ * 200 + o] = (short)f2bfu(qa[n6][r2]);
        }
    __syncthreads();
#pragma unroll
    for (int j = 0; j < 3; ++j) {
        int flat = t * 3 + j;
        int row = flat / 24, c16 = (flat % 24) * 8;
        *(uint4*)&qkv[((bh << 6) + row) * 192 + c16] = *(uint4*)&qstage[row * 200 + c16];
    }
}

// C: local attention (bf16 single-pass K+V staging) + out-proj/MLP on MFMA
__global__ __launch_bounds__(512) void k_attn_ff(
    const bf16* __restrict__ qkv, float* __restrict__ xio,
    const float* __restrict__ c0buf, const short* __restrict__ outs,
    const short* __restrict__ ff1s, const short* __restrict__ ff2s,
    const void* __restrict__ outb, const void* __restrict__ ln2w,
    const void* __restrict__ ln2b, const void* __restrict__ ff1b,
    const void* __restrict__ ff2b, const int* __restrict__ mflags,
    void* __restrict__ dout, int write_out)
{
    // kvb bf16 [128ch][199] = 50944 B (ch 0..63 K, 64..127 V).
    // After PV: Ao bf16[64][72] @0; ts f32[64][65] @9216; ys bf16[64][72] @25856;
    // hs bf16[64][72] @35072.
    __shared__ __align__(16) char smraw[50944];
    short* kvb = (short*)smraw;
    short* Ao  = (short*)smraw;
    float* ts  = (float*)(smraw + 9216);
    short* ys  = (short*)(smraw + 25856);
    short* hs  = (short*)(smraw + 35072);

    int md = mflags[1];
    int bh = blockIdx.x;
    int b = bh >> 6, h = bh & 63;
    int t = threadIdx.x;

    // zero halos: 128 ch x 3 rows x 2 slots
    if (t < 384) {
        int c = t & 127, r = t >> 7;
        kvb[c * 199 + r * 66]      = 0;
        kvb[c * 199 + r * 66 + 65] = 0;
    }
    // single-pass K+V staging (combined channel 0..127 <- qkv channel 64..191)
    for (int e = t; e < 3072; e += 512) {
        int c8 = (e & 15) * 8, w = (e >> 4) & 63, r = e >> 10;
        int hr = h - 1 + r;
        union { uint4 u; short s[8]; } rv;
        if (hr >= 0 && hr <= 63) {
            rv.u = *(const uint4*)(qkv + ((b * 64 + hr) * 64 + w) * 192 + 64 + c8);
        } else {
            rv.u = make_uint4(0, 0, 0, 0);
        }
#pragma unroll
        for (int j = 0; j < 8; ++j) kvb[(c8 + j) * 199 + r * 66 + w + 1] = rv.s[j];
    }
    __syncthreads();

    int head = __builtin_amdgcn_readfirstlane((t >> 6) & 3);
    int pos  = t & 63;
    float q[16];
    {
        const bf16* qr = qkv + (((b * 64 + h) * 64) + pos) * 192 + head * 16;
        ld_bf8(qr, q); ld_bf8(qr + 8, q + 8);
    }

    float a[9];
#pragma unroll
    for (int r = 0; r < 3; ++r)
#pragma unroll
        for (int cxi = 0; cxi < 3; ++cxi) {
            float dot = 0.f;
#pragma unroll
            for (int d = 0; d < 16; ++d)
                dot = fmaf(q[d], su2f(kvb[(head * 16 + d) * 199 + r * 66 + pos + cxi]), dot);
            a[r * 3 + cxi] = dot * 0.25f;
        }
    float mx = a[0];
#pragma unroll
    for (int k = 1; k < 9; ++k) mx = fmaxf(mx, a[k]);
    float ssum = 0.f;
#pragma unroll
    for (int k = 0; k < 9; ++k) { a[k] = __expf(a[k] - mx); ssum += a[k]; }
    float inv = 1.f / ssum;
#pragma unroll
    for (int k = 0; k < 9; ++k) a[k] *= inv;

    float o[16];
#pragma unroll
    for (int d = 0; d < 16; ++d) {
        float ov = 0.f;
#pragma unroll
        for (int r = 0; r < 3; ++r)
#pragma unroll
            for (int cxi = 0; cxi < 3; ++cxi)
                ov = fmaf(a[r * 3 + cxi],
                          su2f(kvb[(64 + head * 16 + d) * 199 + r * 66 + pos + cxi]), ov);
        o[d] = ov;
    }
    __syncthreads();   // kv dead

    if (t < 256) {
        *(uint4*)&Ao[pos * 72 + head * 16]     = pk_bf8(o);
        *(uint4*)&Ao[pos * 72 + head * 16 + 8] = pk_bf8(o + 8);
    }
    __syncthreads();

    int og = __builtin_amdgcn_readfirstlane(t >> 6);
    int l = t & 63, nl = l & 15, qd = l >> 4;
    int mt = og & 3;
    int nt0 = (og >> 2) * 2;
    int o0 = nt0 * 16 + nl, o1 = o0 + 16;

    // out-proj MFMA
    {
        f32x4 pa0 = (f32x4){0.f,0.f,0.f,0.f}, pa1 = (f32x4){0.f,0.f,0.f,0.f};
#pragma unroll
        for (int kt = 0; kt < 2; ++kt) {
            bf16x8 av = *(const bf16x8*)&Ao[(mt * 16 + nl) * 72 + kt * 32 + qd * 8];
            bf16x8 b0 = *(const bf16x8*)(outs + o0 * 64 + kt * 32 + qd * 8);
            bf16x8 b1 = *(const bf16x8*)(outs + o1 * 64 + kt * 32 + qd * 8);
            pa0 = __builtin_amdgcn_mfma_f32_16x16x32_bf16(av, b0, pa0, 0, 0, 0);
            pa1 = __builtin_amdgcn_mfma_f32_16x16x32_bf16(av, b1, pa1, 0, 0, 0);
        }
        float ob0 = ldp(outb, o0, md), ob1 = ldp(outb, o1, md);
#pragma unroll
        for (int r2 = 0; r2 < 4; ++r2) {
            int m = mt * 16 + qd * 4 + r2;
            ts[m * 65 + o0] = pa0[r2] + ob0;
            ts[m * 65 + o1] = pa1[r2] + ob1;
        }
    }
    __syncthreads();

    int idx = ((bh << 6) + pos) * 64 + (t >> 6) * 8;
    {
        int cg2 = t >> 6;
        float4 x0 = *(const float4*)&xio[idx];
        float4 x1 = *(const float4*)&xio[idx + 4];
        float* tp = &ts[pos * 65 + cg2 * 8];
        tp[0] += x0.x; tp[1] += x0.y; tp[2] += x0.z; tp[3] += x0.w;
        tp[4] += x1.x; tp[5] += x1.y; tp[6] += x1.z; tp[7] += x1.w;
    }
    __syncthreads();

    // ln2 parallel -> ys bf16
    {
        int tok = t >> 3, j8 = (t & 7) * 8;
        float v[8];
        float ls = 0.f, lq = 0.f;
#pragma unroll
        for (int ci = 0; ci < 8; ++ci) {
            v[ci] = ts[tok * 65 + j8 + ci];
            ls += v[ci]; lq += v[ci] * v[ci];
        }
#pragma unroll
        for (int off = 1; off < 8; off <<= 1) {
            ls += __shfl_xor(ls, off, 64);
            lq += __shfl_xor(lq, off, 64);
        }
        float mu = ls * (1.f / 64.f);
        float vr = lq * (1.f / 64.f) - mu * mu;
        float rs = rsqrtf(fmaxf(vr, 0.f) + 1e-5f);
        float wv[8], bv[8], yv[8];
        ldp8(ln2w, j8, md, wv);
        ldp8(ln2b, j8, md, bv);
#pragma unroll
        for (int ci = 0; ci < 8; ++ci) yv[ci] = (v[ci] - mu) * rs * wv[ci] + bv[ci];
        *(uint4*)&ys[tok * 72 + j8] = pk_bf8(yv);
    }
    __syncthreads();

    // MLP1 + GELU -> hs
    {
        f32x4 ma0 = (f32x4){0.f,0.f,0.f,0.f}, ma1 = (f32x4){0.f,0.f,0.f,0.f};
#pragma unroll
        for (int kt = 0; kt < 2; ++kt) {
            bf16x8 av = *(const bf16x8*)&ys[(mt * 16 + nl) * 72 + kt * 32 + qd * 8];
            bf16x8 b0 = *(const bf16x8*)(ff1s + o0 * 64 + kt * 32 + qd * 8);
            bf16x8 b1 = *(const bf16x8*)(ff1s + o1 * 64 + kt * 32 + qd * 8);
            ma0 = __builtin_amdgcn_mfma_f32_16x16x32_bf16(av, b0, ma0, 0, 0, 0);
            ma1 = __builtin_amdgcn_mfma_f32_16x16x32_bf16(av, b1, ma1, 0, 0, 0);
        }
        float f1b0 = ldp(ff1b, o0, md), f1b1 = ldp(ff1b, o1, md);
#pragma unroll
        for (int r2 = 0; r2 < 4; ++r2) {
            int m = mt * 16 + qd * 4 + r2;
            float v0 = ma0[r2] + f1b0;
            float v1 = ma1[r2] + f1b1;
            hs[m * 72 + o0] = (short)f2bfu(0.5f * v0 * (1.f + erff(v0 * 0.70710678118654752f)));
            hs[m * 72 + o1] = (short)f2bfu(0.5f * v1 * (1.f + erff(v1 * 0.70710678118654752f)));
        }
    }
    __syncthreads();

    // MLP2 + residual into ts
    {
        f32x4 fa0 = (f32x4){0.f,0.f,0.f,0.f}, fa1 = (f32x4){0.f,0.f,0.f,0.f};
#pragma unroll
        for (int kt = 0; kt < 2; ++kt) {
            bf16x8 av = *(const bf16x8*)&hs[(mt * 16 + nl) * 72 + kt * 32 + qd * 8];
            bf16x8 b0 = *(const bf16x8*)(ff2s + o0 * 64 + kt * 32 + qd * 8);
            bf16x8 b1 = *(const bf16x8*)(ff2s + o1 * 64 + kt * 32 + qd * 8);
            fa0 = __builtin_amdgcn_mfma_f32_16x16x32_bf16(av, b0, fa0, 0, 0, 0);
            fa1 = __builtin_amdgcn_mfma_f32_16x16x32_bf16(av, b1, fa1, 0, 0, 0);
        }
        float f2b0 = ldp(ff2b, o0, md), f2b1 = ldp(ff2b, o1, md);
#pragma unroll
        for (int r2 = 0; r2 < 4; ++r2) {
            int m = mt * 16 + qd * 4 + r2;
            ts[m * 65 + o0] += fa0[r2] + f2b0;
            ts[m * 65 + o1] += fa1[r2] + f2b1;
        }
    }
    __syncthreads();

    {
        int cg2 = t >> 6;
        float fv[8];
#pragma unroll
        for (int ci = 0; ci < 8; ++ci) {
            float v = ts[pos * 65 + cg2 * 8 + ci];
            if (cg2 == 0 && ci == 0) v = c0buf[(bh << 6) + pos];
            fv[ci] = finz(v);
        }
        *(float4*)&xio[idx]     = make_float4(fv[0], fv[1], fv[2], fv[3]);
        *(float4*)&xio[idx + 4] = make_float4(fv[4], fv[5], fv[6], fv[7]);
        if (write_out) {
            if (md) {
                *(float4*)&((float*)dout)[idx]     = make_float4(fv[0], fv[1], fv[2], fv[3]);
                *(float4*)&((float*)dout)[idx + 4] = make_float4(fv[4], fv[5], fv[6], fv[7]);
            } else {
                *(uint4*)&((bf16*)dout)[idx] = pk_bf8(fv);
            }
        }
    }
}

// ---------------- launch ----------------

extern "C" void kernel_launch(void* const* d_in, const int* in_sizes, int n_in,
                              void* d_out, int out_size, void* d_ws, size_t ws_size,
                              hipStream_t stream) {
    (void)in_sizes; (void)n_in; (void)out_size; (void)ws_size;
    const void* x     = d_in[0];
    const void* masks = d_in[1];
    const void* p0w   = d_in[2];
    const void* p0b   = d_in[3];
    const void* p1w   = d_in[4];
    const void* p1b   = d_in[5];
    const void* fc0w  = d_in[6];
    const void* fc0b  = d_in[7];
    const void* fc1w  = d_in[8];
    const void* n0w   = d_in[9];
    const void* n0b   = d_in[10];
    const void* ln1w  = d_in[11];
    const void* ln1b  = d_in[12];
    const void* qkvw  = d_in[13];
    const void* outw  = d_in[14];
    const void* outb  = d_in[15];
    const void* ln2w  = d_in[16];
    const void* ln2b  = d_in[17];
    const void* ff1w  = d_in[18];
    const void* ff1b  = d_in[19];
    const void* ff2w  = d_in[20];
    const void* ff2b  = d_in[21];

    char* wsb = (char*)d_ws;
    float* xst      = (float*)(wsb + 0);           //  8,388,608 B fp32 state
    bf16*  qkvb     = (bf16*) (wsb + 8388608);     // 12,582,912 B (aliases hd)
    bf16*  hd       = (bf16*) (wsb + 8388608);
    float* c0buf    = (float*)(wsb + 20971520);    //    131,072 B
    short* bt1      = (short*)(wsb + 21102592);    //    147,456 B
    short* packbase = (short*)(wsb + 21250048);    //    114,688 B
    float* accv     = (float*)(wsb + 21364736);    //        384 B
    int*   mflags   = (int*)  (wsb + 21365120);    //         16 B

    const short* fc0s = packbase;
    const short* fc1s = packbase + 24576;
    const short* qkvs = packbase + 32768;
    const short* outs = packbase + 45056;
    const short* ff1s = packbase + 49152;
    const short* ff2s = packbase + 53248;

    k_detect<<<1, 256, 0, stream>>>((const uint4*)masks, (const uint4*)x, mflags, accv);
    k_cast<<<1024, 256, 0, stream>>>(x, xst, mflags, 262144);
    k_pack_bt1<<<288, 256, 0, stream>>>(p0w, p1w, bt1, mflags);
    k_pack_all<<<224, 256, 0, stream>>>(fc0w, fc1w, qkvw, outw, ff1w, ff2w,
                                        packbase, mflags);

    for (int s = 0; s < NSTEP; ++s) {
        k_perceive<<<512, 512, 0, stream>>>(xst, bt1, fc0s, p0b, p1b, fc0b,
                                            mflags, hd, accv, s);
        k_update_qkv<<<512, 512, 0, stream>>>(xst, hd, fc1s, n0w, n0b, masks,
                                              mflags, accv, c0buf, qkvs,
                                              ln1w, ln1b, qkvb, s);
        k_attn_ff<<<512, 512, 0, stream>>>(qkvb, xst, c0buf, outs, ff1s, ff2s,
                                           outb, ln2w, ln2b, ff1b, ff2b, mflags,
                                           d_out, (s == NSTEP - 1) ? 1 : 0);
    }
}

// Round 12
// 736.756 us; speedup vs baseline: 4.3285x; 1.0485x over previous
//
#include <hip/hip_runtime.h>
#include <hip/hip_bf16.h>

typedef __hip_bfloat16 bf16;
typedef __attribute__((ext_vector_type(8))) short bf16x8;
typedef __attribute__((ext_vector_type(4))) float f32x4;

#define NSTEP 6

static __device__ __forceinline__ float b2f(bf16 v) { return __bfloat162float(v); }

static __device__ __forceinline__ float ldp(const void* p, int i, int md) {
    return md ? ((const float*)p)[i] : b2f(((const bf16*)p)[i]);
}
static __device__ __forceinline__ float finz(float v) {
    return (v == v && v * 0.0f == 0.0f) ? v : 0.0f;
}
static __device__ __forceinline__ unsigned short f2bfu(float v) {
    bf16 h = __float2bfloat16(v);
    return *(unsigned short*)&h;
}
static __device__ __forceinline__ void ld_bf8(const bf16* p, float* f) {
    union { uint4 u; unsigned short s[8]; } r;
    r.u = *(const uint4*)p;
#pragma unroll
    for (int j = 0; j < 8; ++j) f[j] = __uint_as_float(((unsigned)r.s[j]) << 16);
}
static __device__ __forceinline__ void ldp8(const void* p, int i, int md, float* f) {
    if (md) {
        const float* fp = (const float*)p + i;
        float4 a = *(const float4*)fp, b = *(const float4*)(fp + 4);
        f[0]=a.x; f[1]=a.y; f[2]=a.z; f[3]=a.w; f[4]=b.x; f[5]=b.y; f[6]=b.z; f[7]=b.w;
    } else {
        ld_bf8((const bf16*)p + i, f);
    }
}
static __device__ __forceinline__ uint4 pk_bf8(const float* f) {
    union { uint4 u; unsigned short s[8]; } r;
#pragma unroll
    for (int j = 0; j < 8; ++j) r.s[j] = f2bfu(f[j]);
    return r.u;
}

// ---------------- setup kernels ----------------

// flags[0]: masks dtype (0 int32, 1 u8, 2 16-bit, 3 f32); flags[1]: floats bf16/f32
__global__ void k_detect(const uint4* __restrict__ m4,
                         const uint4* __restrict__ x4,
                         int* __restrict__ flags, float* __restrict__ accv) {
    __shared__ int s3f, sup, slo, sf32;
    int t = threadIdx.x;
    if (t == 0) { s3f = 0; sup = 0; slo = 0; sf32 = 0; }
    if (t < 96) accv[t] = 0.f;
    __syncthreads();
    int l3f = 0, lup = 0, llo = 0, lf = 0;
    for (int i = t; i < 3072; i += 256) {
        uint4 v = m4[i];
        const unsigned* d = (const unsigned*)&v;
#pragma unroll
        for (int j = 0; j < 4; ++j) {
            unsigned w = d[j];
            unsigned x3f = w ^ 0x3F3F3F3Fu;
            if ((x3f - 0x01010101u) & ~x3f & 0x80808080u) l3f = 1;
            if (w & 0xFFFFFF00u) lup = 1;
            if (w & 0x0000FFFFu) llo = 1;
        }
    }
    for (int i = t; i < 4096; i += 256) {
        uint4 v = x4[i];
        const unsigned* d = (const unsigned*)&v;
#pragma unroll
        for (int j = 0; j < 4; ++j) {
            unsigned bb = (d[j] >> 8) & 0x7Fu;
            if (bb > 0x48u) lf = 1;
        }
    }
    if (l3f) atomicOr(&s3f, 1);
    if (lup) atomicOr(&sup, 1);
    if (llo) atomicOr(&slo, 1);
    if (lf)  atomicOr(&sf32, 1);
    __syncthreads();
    if (t == 0) {
        int mode;
        if (!s3f && !sup) mode = 0;
        else if (!s3f)    mode = 1;
        else if (slo)     mode = 2;
        else              mode = 3;
        flags[0] = mode;
        flags[1] = sf32;
    }
}

__global__ void k_cast(const void* __restrict__ in, float* __restrict__ out,
                       const int* __restrict__ mflags, int n8) {
    int md = mflags[1];
    int i = blockIdx.x * 256 + threadIdx.x;
    if (i < n8) {
        float f[8];
        ldp8(in, i * 8, md, f);
#pragma unroll
        for (int j = 0; j < 8; ++j) f[j] = finz(f[j]);
        *(float4*)&out[i * 8]     = make_float4(f[0], f[1], f[2], f[3]);
        *(float4*)&out[i * 8 + 4] = make_float4(f[4], f[5], f[6], f[7]);
    }
}

// bt1[o][k] bf16, k = (ky*3+kx)*64 + i
__global__ void k_pack_bt1(const void* __restrict__ p0, const void* __restrict__ p1,
                           short* __restrict__ out, const int* __restrict__ mflags) {
    int md = mflags[1];
    int i = blockIdx.x * 256 + threadIdx.x;
    if (i < 128 * 576) {
        int o = i / 576, k = i % 576;
        int kk = k >> 6, ii = k & 63;
        float v = (o < 64) ? ldp(p0, o * 576 + ii * 9 + kk, md)
                           : ldp(p1, (o - 64) * 576 + ii * 9 + kk, md);
        out[i] = (short)f2bfu(v);
    }
}

__global__ void k_pack_all(const void* __restrict__ fc0w, const void* __restrict__ fc1w,
                           const void* __restrict__ qkvw, const void* __restrict__ outw,
                           const void* __restrict__ ff1w, const void* __restrict__ ff2w,
                           short* __restrict__ out, const int* __restrict__ mflags) {
    int md = mflags[1];
    int i = blockIdx.x * 256 + threadIdx.x;
    if (i < 57344) {
        float v;
        if (i < 24576)      v = ldp(fc0w, i, md);
        else if (i < 32768) v = ldp(fc1w, i - 24576, md);
        else if (i < 45056) v = ldp(qkvw, i - 32768, md);
        else if (i < 49152) v = ldp(outw, i - 45056, md);
        else if (i < 53248) v = ldp(ff1w, i - 49152, md);
        else                v = ldp(ff2w, i - 53248, md);
        out[i] = (short)f2bfu(v);
    }
}

// ---------------- step kernels: grid 512, 512 threads, 3 blocks/CU ----------

// A: conv-as-implicit-GEMM [64x128x576] + fc0 GEMM [64x128x192], MFMA
__global__ __launch_bounds__(512, 6) void k_perceive(
    const float* __restrict__ xin, const short* __restrict__ bt1,
    const short* __restrict__ fc0s, const void* __restrict__ p0b,
    const void* __restrict__ p1b, const void* __restrict__ fc0b,
    const int* __restrict__ mflags, bf16* __restrict__ hd,
    float* __restrict__ accv, int step)
{
    __shared__ __align__(16) short xpad_s[3 * 66 * 72];
    __shared__ __align__(16) short P_s[64 * 200];
    __shared__ float red[32];
    int md = mflags[1];
    int bh = blockIdx.x;
    int b = bh >> 6, h = bh & 63;
    int t = threadIdx.x;

    for (int e = t; e < 1536; e += 512) {
        int c8 = e & 7, w = (e >> 3) & 63, r = e >> 9;
        int hr = h - 1 + r; hr = hr < 0 ? -hr : (hr > 63 ? 126 - hr : hr);
        const float* src = xin + ((((b << 6) + hr) << 6) | w) * 64 + c8 * 8;
        float f[8];
        float4 v0 = *(const float4*)src, v1 = *(const float4*)(src + 4);
        f[0]=v0.x; f[1]=v0.y; f[2]=v0.z; f[3]=v0.w; f[4]=v1.x; f[5]=v1.y; f[6]=v1.z; f[7]=v1.w;
        uint4 pv = pk_bf8(f);
        *(uint4*)&xpad_s[((r * 66) + w + 1) * 72 + c8 * 8] = pv;
        if (r == 1) *(uint4*)&P_s[w * 200 + c8 * 8] = pv;
    }
    if (t < 48) {
        int c8 = t & 7, side = (t >> 3) & 1, r = t >> 4;
        int hr = h - 1 + r; hr = hr < 0 ? -hr : (hr > 63 ? 126 - hr : hr);
        int wsrc = side ? 62 : 1, wp = side ? 65 : 0;
        const float* src = xin + ((((b << 6) + hr) << 6) | wsrc) * 64 + c8 * 8;
        float f[8];
        float4 v0 = *(const float4*)src, v1 = *(const float4*)(src + 4);
        f[0]=v0.x; f[1]=v0.y; f[2]=v0.z; f[3]=v0.w; f[4]=v1.x; f[5]=v1.y; f[6]=v1.z; f[7]=v1.w;
        *(uint4*)&xpad_s[((r * 66) + wp) * 72 + c8 * 8] = pk_bf8(f);
    }
    __syncthreads();

    int og  = __builtin_amdgcn_readfirstlane(t >> 6);
    int l   = t & 63, nl = l & 15, q = l >> 4;
    int mt0 = (og & 1) * 2;
    int nt0 = (og >> 1) * 2;
    int o0  = nt0 * 16 + nl, o1 = o0 + 16;

    f32x4 acc[2][2];
#pragma unroll
    for (int i = 0; i < 2; ++i)
#pragma unroll
        for (int j = 0; j < 2; ++j) acc[i][j] = (f32x4){0.f, 0.f, 0.f, 0.f};

    for (int kt = 0; kt < 18; ++kt) {
        int kk = kt >> 1, c0 = (kt & 1) << 5;
        int r = kk / 3, cxi = kk - r * 3;
        bf16x8 b0 = *(const bf16x8*)(bt1 + o0 * 576 + kt * 32 + q * 8);
        bf16x8 b1 = *(const bf16x8*)(bt1 + o1 * 576 + kt * 32 + q * 8);
        bf16x8 a0 = *(const bf16x8*)&xpad_s[((r * 66) + mt0 * 16 + nl + cxi) * 72 + c0 + q * 8];
        bf16x8 a1 = *(const bf16x8*)&xpad_s[((r * 66) + mt0 * 16 + 16 + nl + cxi) * 72 + c0 + q * 8];
        acc[0][0] = __builtin_amdgcn_mfma_f32_16x16x32_bf16(a0, b0, acc[0][0], 0, 0, 0);
        acc[0][1] = __builtin_amdgcn_mfma_f32_16x16x32_bf16(a0, b1, acc[0][1], 0, 0, 0);
        acc[1][0] = __builtin_amdgcn_mfma_f32_16x16x32_bf16(a1, b0, acc[1][0], 0, 0, 0);
        acc[1][1] = __builtin_amdgcn_mfma_f32_16x16x32_bf16(a1, b1, acc[1][1], 0, 0, 0);
    }
    {
        float bias0 = (o0 < 64) ? ldp(p0b, o0, md) : ldp(p1b, o0 - 64, md);
        float bias1 = (o1 < 64) ? ldp(p0b, o1, md) : ldp(p1b, o1 - 64, md);
#pragma unroll
        for (int i = 0; i < 2; ++i)
#pragma unroll
            for (int j = 0; j < 2; ++j) {
                int oo = j ? o1 : o0;
                float bb = j ? bias1 : bias0;
#pragma unroll
                for (int r2 = 0; r2 < 4; ++r2) {
                    int m = (mt0 + i) * 16 + q * 4 + r2;
                    P_s[m * 200 + 64 + oo] = (short)f2bfu(acc[i][j][r2] + bb);
                }
            }
    }
    __syncthreads();

#pragma unroll
    for (int i = 0; i < 2; ++i)
#pragma unroll
        for (int j = 0; j < 2; ++j) acc[i][j] = (f32x4){0.f, 0.f, 0.f, 0.f};
    for (int kt = 0; kt < 6; ++kt) {
        bf16x8 b0 = *(const bf16x8*)(fc0s + o0 * 192 + kt * 32 + q * 8);
        bf16x8 b1 = *(const bf16x8*)(fc0s + o1 * 192 + kt * 32 + q * 8);
        bf16x8 a0 = *(const bf16x8*)&P_s[(mt0 * 16 + nl) * 200 + kt * 32 + q * 8];
        bf16x8 a1 = *(const bf16x8*)&P_s[(mt0 * 16 + 16 + nl) * 200 + kt * 32 + q * 8];
        acc[0][0] = __builtin_amdgcn_mfma_f32_16x16x32_bf16(a0, b0, acc[0][0], 0, 0, 0);
        acc[0][1] = __builtin_amdgcn_mfma_f32_16x16x32_bf16(a0, b1, acc[0][1], 0, 0, 0);
        acc[1][0] = __builtin_amdgcn_mfma_f32_16x16x32_bf16(a1, b0, acc[1][0], 0, 0, 0);
        acc[1][1] = __builtin_amdgcn_mfma_f32_16x16x32_bf16(a1, b1, acc[1][1], 0, 0, 0);
    }
    float lsum = 0.f, lsq = 0.f;
    {
        float fb0 = ldp(fc0b, o0, md), fb1 = ldp(fc0b, o1, md);
#pragma unroll
        for (int i = 0; i < 2; ++i)
#pragma unroll
            for (int j = 0; j < 2; ++j) {
                int oo = j ? o1 : o0;
                float bb = j ? fb1 : fb0;
#pragma unroll
                for (int r2 = 0; r2 < 4; ++r2) {
                    int m = (mt0 + i) * 16 + q * 4 + r2;
                    float v = fmaxf(acc[i][j][r2] + bb, 0.f);
                    unsigned short hu = f2bfu(v);
                    hd[((bh << 6) + m) * 128 + oo] = *(bf16*)&hu;
                    float vr = __uint_as_float(((unsigned)hu) << 16);
                    lsum += vr; lsq += vr * vr;
                }
            }
    }
#pragma unroll
    for (int off = 32; off > 0; off >>= 1) {
        lsum += __shfl_down(lsum, off, 64);
        lsq  += __shfl_down(lsq,  off, 64);
    }
    if (l == 0) { red[og] = lsum; red[16 + og] = lsq; }
    __syncthreads();
    if (t == 0) {
        float a = 0.f, s2 = 0.f;
#pragma unroll
        for (int w = 0; w < 8; ++w) { a += red[w]; s2 += red[16 + w]; }
        atomicAdd(&accv[step * 16 + b * 2],     a);
        atomicAdd(&accv[step * 16 + b * 2 + 1], s2);
    }
}

// B: LN0 + fc1 (MFMA) + mask/residual + parallel ln1 + qkv (MFMA)
__global__ __launch_bounds__(512, 6) void k_update_qkv(
    float* __restrict__ xio, const bf16* __restrict__ hd,
    const short* __restrict__ fc1s, const void* __restrict__ n0w,
    const void* __restrict__ n0b, const void* __restrict__ mraw,
    const int* __restrict__ mflags, const float* __restrict__ accv,
    float* __restrict__ c0buf, const short* __restrict__ qkvs,
    const void* __restrict__ ln1w, const void* __restrict__ ln1b,
    bf16* __restrict__ qkv, int step)
{
    __shared__ __align__(16) char UQ[44288];
    short* hdnb   = (short*)UQ;            // bf16[64][136]
    float* xrowf  = (float*)(UQ + 17408);  // f32[64][68]
    short* ysb    = (short*)(UQ + 34816);  // bf16[64][72]
    short* qstage = (short*)UQ;            // bf16[64][200] after hdnb/xrowf dead

    int md = mflags[1];
    int mmode = mflags[0];
    int bh = blockIdx.x;
    int b = bh >> 6, h = bh & 63;
    int t = threadIdx.x;
    int og = __builtin_amdgcn_readfirstlane(t >> 6);
    int l = t & 63, nl = l & 15, qd = l >> 4;

    const float invN = 1.f / 524288.f;
    float mean = accv[step * 16 + b * 2] * invN;
    float var  = accv[step * 16 + b * 2 + 1] * invN - mean * mean;
    float rstd = rsqrtf(fmaxf(var, 0.f) + 1e-5f);

    const bf16* hrow = hd + ((b * 64 + h) * 64) * 128;
    for (int e = t; e < 1024; e += 512) {
        int pos = e >> 4, j8 = (e & 15) * 8;
        float hv[8], wv[8], bv[8], ov[8];
        ld_bf8(hrow + pos * 128 + j8, hv);
        int ni = (h * 64 + pos) * 128 + j8;
        ldp8(n0w, ni, md, wv);
        ldp8(n0b, ni, md, bv);
#pragma unroll
        for (int j = 0; j < 8; ++j) ov[j] = (hv[j] - mean) * rstd * wv[j] + bv[j];
        *(uint4*)&hdnb[pos * 136 + j8] = pk_bf8(ov);
    }
    {
        int pos = t >> 3, c8 = (t & 7) * 8;
        const float* src = xio + ((bh << 6) + pos) * 64 + c8;
        *(float4*)&xrowf[pos * 68 + c8]     = *(const float4*)src;
        *(float4*)&xrowf[pos * 68 + c8 + 4] = *(const float4*)(src + 4);
    }
    __syncthreads();

    // fc1 MFMA: M=64, N=64, K=128
    int mt = og & 3;
    int nt0 = (og >> 2) * 2;
    int o0 = nt0 * 16 + nl, o1 = o0 + 16;
    f32x4 f0 = (f32x4){0.f,0.f,0.f,0.f}, f1 = (f32x4){0.f,0.f,0.f,0.f};
#pragma unroll
    for (int kt = 0; kt < 4; ++kt) {
        bf16x8 av = *(const bf16x8*)&hdnb[(mt * 16 + nl) * 136 + kt * 32 + qd * 8];
        bf16x8 b0 = *(const bf16x8*)(fc1s + o0 * 128 + kt * 32 + qd * 8);
        bf16x8 b1 = *(const bf16x8*)(fc1s + o1 * 128 + kt * 32 + qd * 8);
        f0 = __builtin_amdgcn_mfma_f32_16x16x32_bf16(av, b0, f0, 0, 0, 0);
        f1 = __builtin_amdgcn_mfma_f32_16x16x32_bf16(av, b1, f1, 0, 0, 0);
    }
    int mk[4];
#pragma unroll
    for (int r2 = 0; r2 < 4; ++r2) {
        int m_ = mt * 16 + qd * 4 + r2;
        int midx = ((step * 8 + b) * 64 + h) * 64 + m_;
        if (mmode == 0)      mk[r2] = ((const int*)mraw)[midx] != 0;
        else if (mmode == 1) mk[r2] = ((const unsigned char*)mraw)[midx] != 0;
        else if (mmode == 2) mk[r2] = ((const unsigned short*)mraw)[midx] != 0;
        else                 mk[r2] = ((const float*)mraw)[midx] != 0.0f;
    }
#pragma unroll
    for (int j = 0; j < 2; ++j)
#pragma unroll
        for (int r2 = 0; r2 < 4; ++r2) {
            int m_ = mt * 16 + qd * 4 + r2;
            int n_ = j ? o1 : o0;
            float xv = xrowf[m_ * 68 + n_];
            if (n_ == 0) c0buf[(bh << 6) + m_] = xv;   // pre-update ch0
            float dx = j ? f1[r2] : f0[r2];
            xrowf[m_ * 68 + n_] = finz(mk[r2] ? (xv + dx) : xv);
        }
    __syncthreads();

    // store xn -> global ; ln1 parallel (8 lanes/token) -> ysb bf16
    {
        int pos = t >> 3, c8 = (t & 7) * 8;
        float v[8];
#pragma unroll
        for (int ci = 0; ci < 8; ++ci) v[ci] = xrowf[pos * 68 + c8 + ci];
        float* dst = xio + ((bh << 6) + pos) * 64 + c8;
        *(float4*)dst       = make_float4(v[0], v[1], v[2], v[3]);
        *(float4*)(dst + 4) = make_float4(v[4], v[5], v[6], v[7]);
        float ls = 0.f, lq = 0.f;
#pragma unroll
        for (int ci = 0; ci < 8; ++ci) { ls += v[ci]; lq += v[ci] * v[ci]; }
#pragma unroll
        for (int off = 1; off < 8; off <<= 1) {
            ls += __shfl_xor(ls, off, 64);
            lq += __shfl_xor(lq, off, 64);
        }
        float mu = ls * (1.f / 64.f);
        float vr = lq * (1.f / 64.f) - mu * mu;
        float rs = rsqrtf(fmaxf(vr, 0.f) + 1e-5f);
        float wv[8], bv[8], yv[8];
        ldp8(ln1w, c8, md, wv);
        ldp8(ln1b, c8, md, bv);
#pragma unroll
        for (int ci = 0; ci < 8; ++ci) yv[ci] = (v[ci] - mu) * rs * wv[ci] + bv[ci];
        *(uint4*)&ysb[pos * 72 + c8] = pk_bf8(yv);
    }
    __syncthreads();

    // qkv MFMA: M=64, N=192, K=64
    int baseN = (og >> 2) * 6;
    f32x4 qa[6];
#pragma unroll
    for (int n6 = 0; n6 < 6; ++n6) qa[n6] = (f32x4){0.f,0.f,0.f,0.f};
#pragma unroll
    for (int kt = 0; kt < 2; ++kt) {
        bf16x8 av = *(const bf16x8*)&ysb[(mt * 16 + nl) * 72 + kt * 32 + qd * 8];
#pragma unroll
        for (int n6 = 0; n6 < 6; ++n6) {
            int o = (baseN + n6) * 16 + nl;
            bf16x8 bq = *(const bf16x8*)(qkvs + o * 64 + kt * 32 + qd * 8);
            qa[n6] = __builtin_amdgcn_mfma_f32_16x16x32_bf16(av, bq, qa[n6], 0, 0, 0);
        }
    }
#pragma unroll
    for (int n6 = 0; n6 < 6; ++n6)
#pragma unroll
        for (int r2 = 0; r2 < 4; ++r2) {
            int m_ = mt * 16 + qd * 4 + r2;
            int o = (baseN + n6) * 16 + nl;
            qstage[m_ * 200 + o] = (short)f2bfu(qa[n6][r2]);
        }
    __syncthreads();
#pragma unroll
    for (int j = 0; j < 3; ++j) {
        int flat = t * 3 + j;
        int row = flat / 24, c16 = (flat % 24) * 8;
        *(uint4*)&qkv[((bh << 6) + row) * 192 + c16] = *(uint4*)&qstage[row * 200 + c16];
    }
}

// C: local attention (two-pass fp32 K/V staging, R8-proven) + MFMA proj/MLP
__global__ __launch_bounds__(512, 6) void k_attn_ff(
    const bf16* __restrict__ qkv, float* __restrict__ xio,
    const float* __restrict__ c0buf, const short* __restrict__ outs,
    const short* __restrict__ ff1s, const short* __restrict__ ff2s,
    const void* __restrict__ outb, const void* __restrict__ ln2w,
    const void* __restrict__ ln2b, const void* __restrict__ ff1b,
    const void* __restrict__ ff2b, const int* __restrict__ mflags,
    void* __restrict__ dout, int write_out)
{
    // kv fp32 [64][199] = 50944 B. After PV: Ao bf16[64][72] @0;
    // ts f32[64][65] @9216; ys bf16[64][72] @25856; hs bf16[64][72] @35072.
    __shared__ __align__(16) char smraw[50944];
    float* kv = (float*)smraw;
    short* Ao = (short*)smraw;
    float* ts = (float*)(smraw + 9216);
    short* ys = (short*)(smraw + 25856);
    short* hs = (short*)(smraw + 35072);

    int md = mflags[1];
    int bh = blockIdx.x;
    int b = bh >> 6, h = bh & 63;
    int t = threadIdx.x;

    if (t < 192) {
        int c = t & 63, r = t >> 6;
        kv[c * 199 + r * 66]      = 0.f;
        kv[c * 199 + r * 66 + 65] = 0.f;
    }
    // K staging
    for (int e = t; e < 1536; e += 512) {
        int c8 = (e & 7) * 8, w = (e >> 3) & 63, r = e >> 9;
        int hr = h - 1 + r;
        float f[8];
        if (hr >= 0 && hr <= 63) {
            ld_bf8(qkv + ((b * 64 + hr) * 64 + w) * 192 + 64 + c8, f);
        } else {
#pragma unroll
            for (int j = 0; j < 8; ++j) f[j] = 0.f;
        }
#pragma unroll
        for (int j = 0; j < 8; ++j) kv[(c8 + j) * 199 + r * 66 + w + 1] = f[j];
    }
    __syncthreads();

    int head = __builtin_amdgcn_readfirstlane((t >> 6) & 3);
    int pos  = t & 63;
    float q[16];
    {
        const bf16* qr = qkv + (((b * 64 + h) * 64) + pos) * 192 + head * 16;
        ld_bf8(qr, q); ld_bf8(qr + 8, q + 8);
    }

    float a[9];
#pragma unroll
    for (int r = 0; r < 3; ++r)
#pragma unroll
        for (int cxi = 0; cxi < 3; ++cxi) {
            float dot = 0.f;
#pragma unroll
            for (int d = 0; d < 16; ++d)
                dot = fmaf(q[d], kv[(head * 16 + d) * 199 + r * 66 + pos + cxi], dot);
            a[r * 3 + cxi] = dot * 0.25f;
        }
    float mx = a[0];
#pragma unroll
    for (int k = 1; k < 9; ++k) mx = fmaxf(mx, a[k]);
    float ssum = 0.f;
#pragma unroll
    for (int k = 0; k < 9; ++k) { a[k] = __expf(a[k] - mx); ssum += a[k]; }
    float inv = 1.f / ssum;
#pragma unroll
    for (int k = 0; k < 9; ++k) a[k] *= inv;
    __syncthreads();

    // V staging
    for (int e = t; e < 1536; e += 512) {
        int c8 = (e & 7) * 8, w = (e >> 3) & 63, r = e >> 9;
        int hr = h - 1 + r;
        float f[8];
        if (hr >= 0 && hr <= 63) {
            ld_bf8(qkv + ((b * 64 + hr) * 64 + w) * 192 + 128 + c8, f);
        } else {
#pragma unroll
            for (int j = 0; j < 8; ++j) f[j] = 0.f;
        }
#pragma unroll
        for (int j = 0; j < 8; ++j) kv[(c8 + j) * 199 + r * 66 + w + 1] = f[j];
    }
    __syncthreads();

    float o[16];
#pragma unroll
    for (int d = 0; d < 16; ++d) {
        float ov = 0.f;
#pragma unroll
        for (int r = 0; r < 3; ++r)
#pragma unroll
            for (int cxi = 0; cxi < 3; ++cxi)
                ov = fmaf(a[r * 3 + cxi], kv[(head * 16 + d) * 199 + r * 66 + pos + cxi], ov);
        o[d] = ov;
    }
    __syncthreads();   // kv dead

    if (t < 256) {
        *(uint4*)&Ao[pos * 72 + head * 16]     = pk_bf8(o);
        *(uint4*)&Ao[pos * 72 + head * 16 + 8] = pk_bf8(o + 8);
    }
    __syncthreads();

    int og = __builtin_amdgcn_readfirstlane(t >> 6);
    int l = t & 63, nl = l & 15, qd = l >> 4;
    int mt = og & 3;
    int nt0 = (og >> 2) * 2;
    int o0 = nt0 * 16 + nl, o1 = o0 + 16;

    // out-proj MFMA
    {
        f32x4 pa0 = (f32x4){0.f,0.f,0.f,0.f}, pa1 = (f32x4){0.f,0.f,0.f,0.f};
#pragma unroll
        for (int kt = 0; kt < 2; ++kt) {
            bf16x8 av = *(const bf16x8*)&Ao[(mt * 16 + nl) * 72 + kt * 32 + qd * 8];
            bf16x8 b0 = *(const bf16x8*)(outs + o0 * 64 + kt * 32 + qd * 8);
            bf16x8 b1 = *(const bf16x8*)(outs + o1 * 64 + kt * 32 + qd * 8);
            pa0 = __builtin_amdgcn_mfma_f32_16x16x32_bf16(av, b0, pa0, 0, 0, 0);
            pa1 = __builtin_amdgcn_mfma_f32_16x16x32_bf16(av, b1, pa1, 0, 0, 0);
        }
        float ob0 = ldp(outb, o0, md), ob1 = ldp(outb, o1, md);
#pragma unroll
        for (int r2 = 0; r2 < 4; ++r2) {
            int m = mt * 16 + qd * 4 + r2;
            ts[m * 65 + o0] = pa0[r2] + ob0;
            ts[m * 65 + o1] = pa1[r2] + ob1;
        }
    }
    __syncthreads();

    int idx = ((bh << 6) + pos) * 64 + (t >> 6) * 8;
    {
        int cg2 = t >> 6;
        float4 x0 = *(const float4*)&xio[idx];
        float4 x1 = *(const float4*)&xio[idx + 4];
        float* tp = &ts[pos * 65 + cg2 * 8];
        tp[0] += x0.x; tp[1] += x0.y; tp[2] += x0.z; tp[3] += x0.w;
        tp[4] += x1.x; tp[5] += x1.y; tp[6] += x1.z; tp[7] += x1.w;
    }
    __syncthreads();

    // ln2 parallel -> ys bf16
    {
        int tok = t >> 3, j8 = (t & 7) * 8;
        float v[8];
        float ls = 0.f, lq = 0.f;
#pragma unroll
        for (int ci = 0; ci < 8; ++ci) {
            v[ci] = ts[tok * 65 + j8 + ci];
            ls += v[ci]; lq += v[ci] * v[ci];
        }
#pragma unroll
        for (int off = 1; off < 8; off <<= 1) {
            ls += __shfl_xor(ls, off, 64);
            lq += __shfl_xor(lq, off, 64);
        }
        float mu = ls * (1.f / 64.f);
        float vr = lq * (1.f / 64.f) - mu * mu;
        float rs = rsqrtf(fmaxf(vr, 0.f) + 1e-5f);
        float wv[8], bv[8], yv[8];
        ldp8(ln2w, j8, md, wv);
        ldp8(ln2b, j8, md, bv);
#pragma unroll
        for (int ci = 0; ci < 8; ++ci) yv[ci] = (v[ci] - mu) * rs * wv[ci] + bv[ci];
        *(uint4*)&ys[tok * 72 + j8] = pk_bf8(yv);
    }
    __syncthreads();

    // MLP1 + GELU -> hs
    {
        f32x4 ma0 = (f32x4){0.f,0.f,0.f,0.f}, ma1 = (f32x4){0.f,0.f,0.f,0.f};
#pragma unroll
        for (int kt = 0; kt < 2; ++kt) {
            bf16x8 av = *(const bf16x8*)&ys[(mt * 16 + nl) * 72 + kt * 32 + qd * 8];
            bf16x8 b0 = *(const bf16x8*)(ff1s + o0 * 64 + kt * 32 + qd * 8);
            bf16x8 b1 = *(const bf16x8*)(ff1s + o1 * 64 + kt * 32 + qd * 8);
            ma0 = __builtin_amdgcn_mfma_f32_16x16x32_bf16(av, b0, ma0, 0, 0, 0);
            ma1 = __builtin_amdgcn_mfma_f32_16x16x32_bf16(av, b1, ma1, 0, 0, 0);
        }
        float f1b0 = ldp(ff1b, o0, md), f1b1 = ldp(ff1b, o1, md);
#pragma unroll
        for (int r2 = 0; r2 < 4; ++r2) {
            int m = mt * 16 + qd * 4 + r2;
            float v0 = ma0[r2] + f1b0;
            float v1 = ma1[r2] + f1b1;
            hs[m * 72 + o0] = (short)f2bfu(0.5f * v0 * (1.f + erff(v0 * 0.70710678118654752f)));
            hs[m * 72 + o1] = (short)f2bfu(0.5f * v1 * (1.f + erff(v1 * 0.70710678118654752f)));
        }
    }
    __syncthreads();

    // MLP2 + residual into ts
    {
        f32x4 fa0 = (f32x4){0.f,0.f,0.f,0.f}, fa1 = (f32x4){0.f,0.f,0.f,0.f};
#pragma unroll
        for (int kt = 0; kt < 2; ++kt) {
            bf16x8 av = *(const bf16x8*)&hs[(mt * 16 + nl) * 72 + kt * 32 + qd * 8];
            bf16x8 b0 = *(const bf16x8*)(ff2s + o0 * 64 + kt * 32 + qd * 8);
            bf16x8 b1 = *(const bf16x8*)(ff2s + o1 * 64 + kt * 32 + qd * 8);
            fa0 = __builtin_amdgcn_mfma_f32_16x16x32_bf16(av, b0, fa0, 0, 0, 0);
            fa1 = __builtin_amdgcn_mfma_f32_16x16x32_bf16(av, b1, fa1, 0, 0, 0);
        }
        float f2b0 = ldp(ff2b, o0, md), f2b1 = ldp(ff2b, o1, md);
#pragma unroll
        for (int r2 = 0; r2 < 4; ++r2) {
            int m = mt * 16 + qd * 4 + r2;
            ts[m * 65 + o0] += fa0[r2] + f2b0;
            ts[m * 65 + o1] += fa1[r2] + f2b1;
        }
    }
    __syncthreads();

    {
        int cg2 = t >> 6;
        float fv[8];
#pragma unroll
        for (int ci = 0; ci < 8; ++ci) {
            float v = ts[pos * 65 + cg2 * 8 + ci];
            if (cg2 == 0 && ci == 0) v = c0buf[(bh << 6) + pos];
            fv[ci] = finz(v);
        }
        *(float4*)&xio[idx]     = make_float4(fv[0], fv[1], fv[2], fv[3]);
        *(float4*)&xio[idx + 4] = make_float4(fv[4], fv[5], fv[6], fv[7]);
        if (write_out) {
            if (md) {
                *(float4*)&((float*)dout)[idx]     = make_float4(fv[0], fv[1], fv[2], fv[3]);
                *(float4*)&((float*)dout)[idx + 4] = make_float4(fv[4], fv[5], fv[6], fv[7]);
            } else {
                *(uint4*)&((bf16*)dout)[idx] = pk_bf8(fv);
            }
        }
    }
}

// ---------------- launch ----------------

extern "C" void kernel_launch(void* const* d_in, const int* in_sizes, int n_in,
                              void* d_out, int out_size, void* d_ws, size_t ws_size,
                              hipStream_t stream) {
    (void)in_sizes; (void)n_in; (void)out_size; (void)ws_size;
    const void* x     = d_in[0];
    const void* masks = d_in[1];
    const void* p0w   = d_in[2];
    const void* p0b   = d_in[3];
    const void* p1w   = d_in[4];
    const void* p1b   = d_in[5];
    const void* fc0w  = d_in[6];
    const void* fc0b  = d_in[7];
    const void* fc1w  = d_in[8];
    const void* n0w   = d_in[9];
    const void* n0b   = d_in[10];
    const void* ln1w  = d_in[11];
    const void* ln1b  = d_in[12];
    const void* qkvw  = d_in[13];
    const void* outw  = d_in[14];
    const void* outb  = d_in[15];
    const void* ln2w  = d_in[16];
    const void* ln2b  = d_in[17];
    const void* ff1w  = d_in[18];
    const void* ff1b  = d_in[19];
    const void* ff2w  = d_in[20];
    const void* ff2b  = d_in[21];

    char* wsb = (char*)d_ws;
    float* xst      = (float*)(wsb + 0);           //  8,388,608 B fp32 state
    bf16*  qkvb     = (bf16*) (wsb + 8388608);     // 12,582,912 B (aliases hd)
    bf16*  hd       = (bf16*) (wsb + 8388608);
    float* c0buf    = (float*)(wsb + 20971520);    //    131,072 B
    short* bt1      = (short*)(wsb + 21102592);    //    147,456 B
    short* packbase = (short*)(wsb + 21250048);    //    114,688 B
    float* accv     = (float*)(wsb + 21364736);    //        384 B
    int*   mflags   = (int*)  (wsb + 21365120);    //         16 B

    const short* fc0s = packbase;
    const short* fc1s = packbase + 24576;
    const short* qkvs = packbase + 32768;
    const short* outs = packbase + 45056;
    const short* ff1s = packbase + 49152;
    const short* ff2s = packbase + 53248;

    k_detect<<<1, 256, 0, stream>>>((const uint4*)masks, (const uint4*)x, mflags, accv);
    k_cast<<<1024, 256, 0, stream>>>(x, xst, mflags, 262144);
    k_pack_bt1<<<288, 256, 0, stream>>>(p0w, p1w, bt1, mflags);
    k_pack_all<<<224, 256, 0, stream>>>(fc0w, fc1w, qkvw, outw, ff1w, ff2w,
                                        packbase, mflags);

    for (int s = 0; s < NSTEP; ++s) {
        k_perceive<<<512, 512, 0, stream>>>(xst, bt1, fc0s, p0b, p1b, fc0b,
                                            mflags, hd, accv, s);
        k_update_qkv<<<512, 512, 0, stream>>>(xst, hd, fc1s, n0w, n0b, masks,
                                              mflags, accv, c0buf, qkvs,
                                              ln1w, ln1b, qkvb, s);
        k_attn_ff<<<512, 512, 0, stream>>>(qkvb, xst, c0buf, outs, ff1s, ff2s,
                                           outb, ln2w, ln2b, ff1b, ff2b, mflags,
                                           d_out, (s == NSTEP - 1) ? 1 : 0);
    }
}

// Round 13
// 729.789 us; speedup vs baseline: 4.3698x; 1.0095x over previous
//
#include <hip/hip_runtime.h>
#include <hip/hip_bf16.h>

typedef __hip_bfloat16 bf16;
typedef __attribute__((ext_vector_type(8))) short bf16x8;
typedef __attribute__((ext_vector_type(4))) float f32x4;

#define NSTEP 6

// XCD-aware swizzle: 512 blocks round-robin over 8 XCDs; map so batch image b
// (bh in [64b,64b+64)) is entirely on XCD b -> halo + cross-kernel L2 reuse.
#define SWIZ_BH(blk) ((((blk) & 7) << 6) | ((blk) >> 3))

static __device__ __forceinline__ float b2f(bf16 v) { return __bfloat162float(v); }

static __device__ __forceinline__ float ldp(const void* p, int i, int md) {
    return md ? ((const float*)p)[i] : b2f(((const bf16*)p)[i]);
}
static __device__ __forceinline__ float finz(float v) {
    return (v == v && v * 0.0f == 0.0f) ? v : 0.0f;
}
static __device__ __forceinline__ unsigned short f2bfu(float v) {
    bf16 h = __float2bfloat16(v);
    return *(unsigned short*)&h;
}
static __device__ __forceinline__ void ld_bf8(const bf16* p, float* f) {
    union { uint4 u; unsigned short s[8]; } r;
    r.u = *(const uint4*)p;
#pragma unroll
    for (int j = 0; j < 8; ++j) f[j] = __uint_as_float(((unsigned)r.s[j]) << 16);
}
static __device__ __forceinline__ void ldp8(const void* p, int i, int md, float* f) {
    if (md) {
        const float* fp = (const float*)p + i;
        float4 a = *(const float4*)fp, b = *(const float4*)(fp + 4);
        f[0]=a.x; f[1]=a.y; f[2]=a.z; f[3]=a.w; f[4]=b.x; f[5]=b.y; f[6]=b.z; f[7]=b.w;
    } else {
        ld_bf8((const bf16*)p + i, f);
    }
}
static __device__ __forceinline__ uint4 pk_bf8(const float* f) {
    union { uint4 u; unsigned short s[8]; } r;
#pragma unroll
    for (int j = 0; j < 8; ++j) r.s[j] = f2bfu(f[j]);
    return r.u;
}

// ---------------- setup kernels ----------------

// flags[0]: masks dtype (0 int32, 1 u8, 2 16-bit, 3 f32); flags[1]: floats bf16/f32
__global__ void k_detect(const uint4* __restrict__ m4,
                         const uint4* __restrict__ x4,
                         int* __restrict__ flags, float* __restrict__ accv) {
    __shared__ int s3f, sup, slo, sf32;
    int t = threadIdx.x;
    if (t == 0) { s3f = 0; sup = 0; slo = 0; sf32 = 0; }
    if (t < 96) accv[t] = 0.f;
    __syncthreads();
    int l3f = 0, lup = 0, llo = 0, lf = 0;
    for (int i = t; i < 3072; i += 256) {
        uint4 v = m4[i];
        const unsigned* d = (const unsigned*)&v;
#pragma unroll
        for (int j = 0; j < 4; ++j) {
            unsigned w = d[j];
            unsigned x3f = w ^ 0x3F3F3F3Fu;
            if ((x3f - 0x01010101u) & ~x3f & 0x80808080u) l3f = 1;
            if (w & 0xFFFFFF00u) lup = 1;
            if (w & 0x0000FFFFu) llo = 1;
        }
    }
    for (int i = t; i < 4096; i += 256) {
        uint4 v = x4[i];
        const unsigned* d = (const unsigned*)&v;
#pragma unroll
        for (int j = 0; j < 4; ++j) {
            unsigned bb = (d[j] >> 8) & 0x7Fu;
            if (bb > 0x48u) lf = 1;
        }
    }
    if (l3f) atomicOr(&s3f, 1);
    if (lup) atomicOr(&sup, 1);
    if (llo) atomicOr(&slo, 1);
    if (lf)  atomicOr(&sf32, 1);
    __syncthreads();
    if (t == 0) {
        int mode;
        if (!s3f && !sup) mode = 0;
        else if (!s3f)    mode = 1;
        else if (slo)     mode = 2;
        else              mode = 3;
        flags[0] = mode;
        flags[1] = sf32;
    }
}

__global__ void k_cast(const void* __restrict__ in, float* __restrict__ out,
                       const int* __restrict__ mflags, int n8) {
    int md = mflags[1];
    int i = blockIdx.x * 256 + threadIdx.x;
    if (i < n8) {
        float f[8];
        ldp8(in, i * 8, md, f);
#pragma unroll
        for (int j = 0; j < 8; ++j) f[j] = finz(f[j]);
        *(float4*)&out[i * 8]     = make_float4(f[0], f[1], f[2], f[3]);
        *(float4*)&out[i * 8 + 4] = make_float4(f[4], f[5], f[6], f[7]);
    }
}

// bt1[o][k] bf16, k = (ky*3+kx)*64 + i
__global__ void k_pack_bt1(const void* __restrict__ p0, const void* __restrict__ p1,
                           short* __restrict__ out, const int* __restrict__ mflags) {
    int md = mflags[1];
    int i = blockIdx.x * 256 + threadIdx.x;
    if (i < 128 * 576) {
        int o = i / 576, k = i % 576;
        int kk = k >> 6, ii = k & 63;
        float v = (o < 64) ? ldp(p0, o * 576 + ii * 9 + kk, md)
                           : ldp(p1, (o - 64) * 576 + ii * 9 + kk, md);
        out[i] = (short)f2bfu(v);
    }
}

__global__ void k_pack_all(const void* __restrict__ fc0w, const void* __restrict__ fc1w,
                           const void* __restrict__ qkvw, const void* __restrict__ outw,
                           const void* __restrict__ ff1w, const void* __restrict__ ff2w,
                           short* __restrict__ out, const int* __restrict__ mflags) {
    int md = mflags[1];
    int i = blockIdx.x * 256 + threadIdx.x;
    if (i < 57344) {
        float v;
        if (i < 24576)      v = ldp(fc0w, i, md);
        else if (i < 32768) v = ldp(fc1w, i - 24576, md);
        else if (i < 45056) v = ldp(qkvw, i - 32768, md);
        else if (i < 49152) v = ldp(outw, i - 45056, md);
        else if (i < 53248) v = ldp(ff1w, i - 49152, md);
        else                v = ldp(ff2w, i - 53248, md);
        out[i] = (short)f2bfu(v);
    }
}

// ---------------- step kernels: grid 512, 512 threads, 3 blocks/CU ----------

// A: conv-as-implicit-GEMM [64x128x576] + fc0 GEMM [64x128x192], MFMA
__global__ __launch_bounds__(512, 6) void k_perceive(
    const float* __restrict__ xin, const short* __restrict__ bt1,
    const short* __restrict__ fc0s, const void* __restrict__ p0b,
    const void* __restrict__ p1b, const void* __restrict__ fc0b,
    const int* __restrict__ mflags, bf16* __restrict__ hd,
    float* __restrict__ accv, int step)
{
    __shared__ __align__(16) short xpad_s[3 * 66 * 72];
    __shared__ __align__(16) short P_s[64 * 200];
    __shared__ float red[32];
    int md = mflags[1];
    int bh = SWIZ_BH(blockIdx.x);
    int b = bh >> 6, h = bh & 63;
    int t = threadIdx.x;

    for (int e = t; e < 1536; e += 512) {
        int c8 = e & 7, w = (e >> 3) & 63, r = e >> 9;
        int hr = h - 1 + r; hr = hr < 0 ? -hr : (hr > 63 ? 126 - hr : hr);
        const float* src = xin + ((((b << 6) + hr) << 6) | w) * 64 + c8 * 8;
        float f[8];
        float4 v0 = *(const float4*)src, v1 = *(const float4*)(src + 4);
        f[0]=v0.x; f[1]=v0.y; f[2]=v0.z; f[3]=v0.w; f[4]=v1.x; f[5]=v1.y; f[6]=v1.z; f[7]=v1.w;
        uint4 pv = pk_bf8(f);
        *(uint4*)&xpad_s[((r * 66) + w + 1) * 72 + c8 * 8] = pv;
        if (r == 1) *(uint4*)&P_s[w * 200 + c8 * 8] = pv;
    }
    if (t < 48) {
        int c8 = t & 7, side = (t >> 3) & 1, r = t >> 4;
        int hr = h - 1 + r; hr = hr < 0 ? -hr : (hr > 63 ? 126 - hr : hr);
        int wsrc = side ? 62 : 1, wp = side ? 65 : 0;
        const float* src = xin + ((((b << 6) + hr) << 6) | wsrc) * 64 + c8 * 8;
        float f[8];
        float4 v0 = *(const float4*)src, v1 = *(const float4*)(src + 4);
        f[0]=v0.x; f[1]=v0.y; f[2]=v0.z; f[3]=v0.w; f[4]=v1.x; f[5]=v1.y; f[6]=v1.z; f[7]=v1.w;
        *(uint4*)&xpad_s[((r * 66) + wp) * 72 + c8 * 8] = pk_bf8(f);
    }
    __syncthreads();

    int og  = __builtin_amdgcn_readfirstlane(t >> 6);
    int l   = t & 63, nl = l & 15, q = l >> 4;
    int mt0 = (og & 1) * 2;
    int nt0 = (og >> 1) * 2;
    int o0  = nt0 * 16 + nl, o1 = o0 + 16;

    f32x4 acc[2][2];
#pragma unroll
    for (int i = 0; i < 2; ++i)
#pragma unroll
        for (int j = 0; j < 2; ++j) acc[i][j] = (f32x4){0.f, 0.f, 0.f, 0.f};

    for (int kt = 0; kt < 18; ++kt) {
        int kk = kt >> 1, c0 = (kt & 1) << 5;
        int r = kk / 3, cxi = kk - r * 3;
        bf16x8 b0 = *(const bf16x8*)(bt1 + o0 * 576 + kt * 32 + q * 8);
        bf16x8 b1 = *(const bf16x8*)(bt1 + o1 * 576 + kt * 32 + q * 8);
        bf16x8 a0 = *(const bf16x8*)&xpad_s[((r * 66) + mt0 * 16 + nl + cxi) * 72 + c0 + q * 8];
        bf16x8 a1 = *(const bf16x8*)&xpad_s[((r * 66) + mt0 * 16 + 16 + nl + cxi) * 72 + c0 + q * 8];
        acc[0][0] = __builtin_amdgcn_mfma_f32_16x16x32_bf16(a0, b0, acc[0][0], 0, 0, 0);
        acc[0][1] = __builtin_amdgcn_mfma_f32_16x16x32_bf16(a0, b1, acc[0][1], 0, 0, 0);
        acc[1][0] = __builtin_amdgcn_mfma_f32_16x16x32_bf16(a1, b0, acc[1][0], 0, 0, 0);
        acc[1][1] = __builtin_amdgcn_mfma_f32_16x16x32_bf16(a1, b1, acc[1][1], 0, 0, 0);
    }
    {
        float bias0 = (o0 < 64) ? ldp(p0b, o0, md) : ldp(p1b, o0 - 64, md);
        float bias1 = (o1 < 64) ? ldp(p0b, o1, md) : ldp(p1b, o1 - 64, md);
#pragma unroll
        for (int i = 0; i < 2; ++i)
#pragma unroll
            for (int j = 0; j < 2; ++j) {
                int oo = j ? o1 : o0;
                float bb = j ? bias1 : bias0;
#pragma unroll
                for (int r2 = 0; r2 < 4; ++r2) {
                    int m = (mt0 + i) * 16 + q * 4 + r2;
                    P_s[m * 200 + 64 + oo] = (short)f2bfu(acc[i][j][r2] + bb);
                }
            }
    }
    __syncthreads();

#pragma unroll
    for (int i = 0; i < 2; ++i)
#pragma unroll
        for (int j = 0; j < 2; ++j) acc[i][j] = (f32x4){0.f, 0.f, 0.f, 0.f};
    for (int kt = 0; kt < 6; ++kt) {
        bf16x8 b0 = *(const bf16x8*)(fc0s + o0 * 192 + kt * 32 + q * 8);
        bf16x8 b1 = *(const bf16x8*)(fc0s + o1 * 192 + kt * 32 + q * 8);
        bf16x8 a0 = *(const bf16x8*)&P_s[(mt0 * 16 + nl) * 200 + kt * 32 + q * 8];
        bf16x8 a1 = *(const bf16x8*)&P_s[(mt0 * 16 + 16 + nl) * 200 + kt * 32 + q * 8];
        acc[0][0] = __builtin_amdgcn_mfma_f32_16x16x32_bf16(a0, b0, acc[0][0], 0, 0, 0);
        acc[0][1] = __builtin_amdgcn_mfma_f32_16x16x32_bf16(a0, b1, acc[0][1], 0, 0, 0);
        acc[1][0] = __builtin_amdgcn_mfma_f32_16x16x32_bf16(a1, b0, acc[1][0], 0, 0, 0);
        acc[1][1] = __builtin_amdgcn_mfma_f32_16x16x32_bf16(a1, b1, acc[1][1], 0, 0, 0);
    }
    float lsum = 0.f, lsq = 0.f;
    {
        float fb0 = ldp(fc0b, o0, md), fb1 = ldp(fc0b, o1, md);
#pragma unroll
        for (int i = 0; i < 2; ++i)
#pragma unroll
            for (int j = 0; j < 2; ++j) {
                int oo = j ? o1 : o0;
                float bb = j ? fb1 : fb0;
#pragma unroll
                for (int r2 = 0; r2 < 4; ++r2) {
                    int m = (mt0 + i) * 16 + q * 4 + r2;
                    float v = fmaxf(acc[i][j][r2] + bb, 0.f);
                    unsigned short hu = f2bfu(v);
                    hd[((bh << 6) + m) * 128 + oo] = *(bf16*)&hu;
                    float vr = __uint_as_float(((unsigned)hu) << 16);
                    lsum += vr; lsq += vr * vr;
                }
            }
    }
#pragma unroll
    for (int off = 32; off > 0; off >>= 1) {
        lsum += __shfl_down(lsum, off, 64);
        lsq  += __shfl_down(lsq,  off, 64);
    }
    if (l == 0) { red[og] = lsum; red[16 + og] = lsq; }
    __syncthreads();
    if (t == 0) {
        float a = 0.f, s2 = 0.f;
#pragma unroll
        for (int w = 0; w < 8; ++w) { a += red[w]; s2 += red[16 + w]; }
        atomicAdd(&accv[step * 16 + b * 2],     a);
        atomicAdd(&accv[step * 16 + b * 2 + 1], s2);
    }
}

// B: LN0 + fc1 (MFMA) + mask/residual + parallel ln1 + qkv (MFMA)
__global__ __launch_bounds__(512, 6) void k_update_qkv(
    float* __restrict__ xio, const bf16* __restrict__ hd,
    const short* __restrict__ fc1s, const void* __restrict__ n0w,
    const void* __restrict__ n0b, const void* __restrict__ mraw,
    const int* __restrict__ mflags, const float* __restrict__ accv,
    float* __restrict__ c0buf, const short* __restrict__ qkvs,
    const void* __restrict__ ln1w, const void* __restrict__ ln1b,
    bf16* __restrict__ qkv, int step)
{
    __shared__ __align__(16) char UQ[44288];
    short* hdnb   = (short*)UQ;            // bf16[64][136]
    float* xrowf  = (float*)(UQ + 17408);  // f32[64][68]
    short* ysb    = (short*)(UQ + 34816);  // bf16[64][72]
    short* qstage = (short*)UQ;            // bf16[64][200] after hdnb/xrowf dead

    int md = mflags[1];
    int mmode = mflags[0];
    int bh = SWIZ_BH(blockIdx.x);
    int b = bh >> 6, h = bh & 63;
    int t = threadIdx.x;
    int og = __builtin_amdgcn_readfirstlane(t >> 6);
    int l = t & 63, nl = l & 15, qd = l >> 4;

    const float invN = 1.f / 524288.f;
    float mean = accv[step * 16 + b * 2] * invN;
    float var  = accv[step * 16 + b * 2 + 1] * invN - mean * mean;
    float rstd = rsqrtf(fmaxf(var, 0.f) + 1e-5f);

    const bf16* hrow = hd + ((b * 64 + h) * 64) * 128;
    for (int e = t; e < 1024; e += 512) {
        int pos = e >> 4, j8 = (e & 15) * 8;
        float hv[8], wv[8], bv[8], ov[8];
        ld_bf8(hrow + pos * 128 + j8, hv);
        int ni = (h * 64 + pos) * 128 + j8;
        ldp8(n0w, ni, md, wv);
        ldp8(n0b, ni, md, bv);
#pragma unroll
        for (int j = 0; j < 8; ++j) ov[j] = (hv[j] - mean) * rstd * wv[j] + bv[j];
        *(uint4*)&hdnb[pos * 136 + j8] = pk_bf8(ov);
    }
    {
        int pos = t >> 3, c8 = (t & 7) * 8;
        const float* src = xio + ((bh << 6) + pos) * 64 + c8;
        *(float4*)&xrowf[pos * 68 + c8]     = *(const float4*)src;
        *(float4*)&xrowf[pos * 68 + c8 + 4] = *(const float4*)(src + 4);
    }
    __syncthreads();

    // fc1 MFMA: M=64, N=64, K=128
    int mt = og & 3;
    int nt0 = (og >> 2) * 2;
    int o0 = nt0 * 16 + nl, o1 = o0 + 16;
    f32x4 f0 = (f32x4){0.f,0.f,0.f,0.f}, f1 = (f32x4){0.f,0.f,0.f,0.f};
#pragma unroll
    for (int kt = 0; kt < 4; ++kt) {
        bf16x8 av = *(const bf16x8*)&hdnb[(mt * 16 + nl) * 136 + kt * 32 + qd * 8];
        bf16x8 b0 = *(const bf16x8*)(fc1s + o0 * 128 + kt * 32 + qd * 8);
        bf16x8 b1 = *(const bf16x8*)(fc1s + o1 * 128 + kt * 32 + qd * 8);
        f0 = __builtin_amdgcn_mfma_f32_16x16x32_bf16(av, b0, f0, 0, 0, 0);
        f1 = __builtin_amdgcn_mfma_f32_16x16x32_bf16(av, b1, f1, 0, 0, 0);
    }
    int mk[4];
#pragma unroll
    for (int r2 = 0; r2 < 4; ++r2) {
        int m_ = mt * 16 + qd * 4 + r2;
        int midx = ((step * 8 + b) * 64 + h) * 64 + m_;
        if (mmode == 0)      mk[r2] = ((const int*)mraw)[midx] != 0;
        else if (mmode == 1) mk[r2] = ((const unsigned char*)mraw)[midx] != 0;
        else if (mmode == 2) mk[r2] = ((const unsigned short*)mraw)[midx] != 0;
        else                 mk[r2] = ((const float*)mraw)[midx] != 0.0f;
    }
#pragma unroll
    for (int j = 0; j < 2; ++j)
#pragma unroll
        for (int r2 = 0; r2 < 4; ++r2) {
            int m_ = mt * 16 + qd * 4 + r2;
            int n_ = j ? o1 : o0;
            float xv = xrowf[m_ * 68 + n_];
            if (n_ == 0) c0buf[(bh << 6) + m_] = xv;   // pre-update ch0
            float dx = j ? f1[r2] : f0[r2];
            xrowf[m_ * 68 + n_] = finz(mk[r2] ? (xv + dx) : xv);
        }
    __syncthreads();

    // store xn -> global ; ln1 parallel (8 lanes/token) -> ysb bf16
    {
        int pos = t >> 3, c8 = (t & 7) * 8;
        float v[8];
#pragma unroll
        for (int ci = 0; ci < 8; ++ci) v[ci] = xrowf[pos * 68 + c8 + ci];
        float* dst = xio + ((bh << 6) + pos) * 64 + c8;
        *(float4*)dst       = make_float4(v[0], v[1], v[2], v[3]);
        *(float4*)(dst + 4) = make_float4(v[4], v[5], v[6], v[7]);
        float ls = 0.f, lq = 0.f;
#pragma unroll
        for (int ci = 0; ci < 8; ++ci) { ls += v[ci]; lq += v[ci] * v[ci]; }
#pragma unroll
        for (int off = 1; off < 8; off <<= 1) {
            ls += __shfl_xor(ls, off, 64);
            lq += __shfl_xor(lq, off, 64);
        }
        float mu = ls * (1.f / 64.f);
        float vr = lq * (1.f / 64.f) - mu * mu;
        float rs = rsqrtf(fmaxf(vr, 0.f) + 1e-5f);
        float wv[8], bv[8], yv[8];
        ldp8(ln1w, c8, md, wv);
        ldp8(ln1b, c8, md, bv);
#pragma unroll
        for (int ci = 0; ci < 8; ++ci) yv[ci] = (v[ci] - mu) * rs * wv[ci] + bv[ci];
        *(uint4*)&ysb[pos * 72 + c8] = pk_bf8(yv);
    }
    __syncthreads();

    // qkv MFMA: M=64, N=192, K=64
    int baseN = (og >> 2) * 6;
    f32x4 qa[6];
#pragma unroll
    for (int n6 = 0; n6 < 6; ++n6) qa[n6] = (f32x4){0.f,0.f,0.f,0.f};
#pragma unroll
    for (int kt = 0; kt < 2; ++kt) {
        bf16x8 av = *(const bf16x8*)&ysb[(mt * 16 + nl) * 72 + kt * 32 + qd * 8];
#pragma unroll
        for (int n6 = 0; n6 < 6; ++n6) {
            int o = (baseN + n6) * 16 + nl;
            bf16x8 bq = *(const bf16x8*)(qkvs + o * 64 + kt * 32 + qd * 8);
            qa[n6] = __builtin_amdgcn_mfma_f32_16x16x32_bf16(av, bq, qa[n6], 0, 0, 0);
        }
    }
#pragma unroll
    for (int n6 = 0; n6 < 6; ++n6)
#pragma unroll
        for (int r2 = 0; r2 < 4; ++r2) {
            int m_ = mt * 16 + qd * 4 + r2;
            int o = (baseN + n6) * 16 + nl;
            qstage[m_ * 200 + o] = (short)f2bfu(qa[n6][r2]);
        }
    __syncthreads();
#pragma unroll
    for (int j = 0; j < 3; ++j) {
        int flat = t * 3 + j;
        int row = flat / 24, c16 = (flat % 24) * 8;
        *(uint4*)&qkv[((bh << 6) + row) * 192 + c16] = *(uint4*)&qstage[row * 200 + c16];
    }
}

// C: local attention (two-pass fp32 K/V staging) + MFMA proj/MLP
__global__ __launch_bounds__(512, 6) void k_attn_ff(
    const bf16* __restrict__ qkv, float* __restrict__ xio,
    const float* __restrict__ c0buf, const short* __restrict__ outs,
    const short* __restrict__ ff1s, const short* __restrict__ ff2s,
    const void* __restrict__ outb, const void* __restrict__ ln2w,
    const void* __restrict__ ln2b, const void* __restrict__ ff1b,
    const void* __restrict__ ff2b, const int* __restrict__ mflags,
    void* __restrict__ dout, int write_out)
{
    // kv fp32 [64][199] = 50944 B. After PV: Ao bf16[64][72] @0;
    // ts f32[64][65] @9216; ys bf16[64][72] @25856; hs bf16[64][72] @35072.
    __shared__ __align__(16) char smraw[50944];
    float* kv = (float*)smraw;
    short* Ao = (short*)smraw;
    float* ts = (float*)(smraw + 9216);
    short* ys = (short*)(smraw + 25856);
    short* hs = (short*)(smraw + 35072);

    int md = mflags[1];
    int bh = SWIZ_BH(blockIdx.x);
    int b = bh >> 6, h = bh & 63;
    int t = threadIdx.x;

    if (t < 192) {
        int c = t & 63, r = t >> 6;
        kv[c * 199 + r * 66]      = 0.f;
        kv[c * 199 + r * 66 + 65] = 0.f;
    }
    // K staging
    for (int e = t; e < 1536; e += 512) {
        int c8 = (e & 7) * 8, w = (e >> 3) & 63, r = e >> 9;
        int hr = h - 1 + r;
        float f[8];
        if (hr >= 0 && hr <= 63) {
            ld_bf8(qkv + ((b * 64 + hr) * 64 + w) * 192 + 64 + c8, f);
        } else {
#pragma unroll
            for (int j = 0; j < 8; ++j) f[j] = 0.f;
        }
#pragma unroll
        for (int j = 0; j < 8; ++j) kv[(c8 + j) * 199 + r * 66 + w + 1] = f[j];
    }
    __syncthreads();

    int head = __builtin_amdgcn_readfirstlane((t >> 6) & 3);
    int pos  = t & 63;
    float q[16];
    {
        const bf16* qr = qkv + (((b * 64 + h) * 64) + pos) * 192 + head * 16;
        ld_bf8(qr, q); ld_bf8(qr + 8, q + 8);
    }

    float a[9];
#pragma unroll
    for (int r = 0; r < 3; ++r)
#pragma unroll
        for (int cxi = 0; cxi < 3; ++cxi) {
            float dot = 0.f;
#pragma unroll
            for (int d = 0; d < 16; ++d)
                dot = fmaf(q[d], kv[(head * 16 + d) * 199 + r * 66 + pos + cxi], dot);
            a[r * 3 + cxi] = dot * 0.25f;
        }
    float mx = a[0];
#pragma unroll
    for (int k = 1; k < 9; ++k) mx = fmaxf(mx, a[k]);
    float ssum = 0.f;
#pragma unroll
    for (int k = 0; k < 9; ++k) { a[k] = __expf(a[k] - mx); ssum += a[k]; }
    float inv = 1.f / ssum;
#pragma unroll
    for (int k = 0; k < 9; ++k) a[k] *= inv;
    __syncthreads();

    // V staging
    for (int e = t; e < 1536; e += 512) {
        int c8 = (e & 7) * 8, w = (e >> 3) & 63, r = e >> 9;
        int hr = h - 1 + r;
        float f[8];
        if (hr >= 0 && hr <= 63) {
            ld_bf8(qkv + ((b * 64 + hr) * 64 + w) * 192 + 128 + c8, f);
        } else {
#pragma unroll
            for (int j = 0; j < 8; ++j) f[j] = 0.f;
        }
#pragma unroll
        for (int j = 0; j < 8; ++j) kv[(c8 + j) * 199 + r * 66 + w + 1] = f[j];
    }
    __syncthreads();

    float o[16];
#pragma unroll
    for (int d = 0; d < 16; ++d) {
        float ov = 0.f;
#pragma unroll
        for (int r = 0; r < 3; ++r)
#pragma unroll
            for (int cxi = 0; cxi < 3; ++cxi)
                ov = fmaf(a[r * 3 + cxi], kv[(head * 16 + d) * 199 + r * 66 + pos + cxi], ov);
        o[d] = ov;
    }
    __syncthreads();   // kv dead

    if (t < 256) {
        *(uint4*)&Ao[pos * 72 + head * 16]     = pk_bf8(o);
        *(uint4*)&Ao[pos * 72 + head * 16 + 8] = pk_bf8(o + 8);
    }
    __syncthreads();

    int og = __builtin_amdgcn_readfirstlane(t >> 6);
    int l = t & 63, nl = l & 15, qd = l >> 4;
    int mt = og & 3;
    int nt0 = (og >> 2) * 2;
    int o0 = nt0 * 16 + nl, o1 = o0 + 16;

    // out-proj MFMA
    {
        f32x4 pa0 = (f32x4){0.f,0.f,0.f,0.f}, pa1 = (f32x4){0.f,0.f,0.f,0.f};
#pragma unroll
        for (int kt = 0; kt < 2; ++kt) {
            bf16x8 av = *(const bf16x8*)&Ao[(mt * 16 + nl) * 72 + kt * 32 + qd * 8];
            bf16x8 b0 = *(const bf16x8*)(outs + o0 * 64 + kt * 32 + qd * 8);
            bf16x8 b1 = *(const bf16x8*)(outs + o1 * 64 + kt * 32 + qd * 8);
            pa0 = __builtin_amdgcn_mfma_f32_16x16x32_bf16(av, b0, pa0, 0, 0, 0);
            pa1 = __builtin_amdgcn_mfma_f32_16x16x32_bf16(av, b1, pa1, 0, 0, 0);
        }
        float ob0 = ldp(outb, o0, md), ob1 = ldp(outb, o1, md);
#pragma unroll
        for (int r2 = 0; r2 < 4; ++r2) {
            int m = mt * 16 + qd * 4 + r2;
            ts[m * 65 + o0] = pa0[r2] + ob0;
            ts[m * 65 + o1] = pa1[r2] + ob1;
        }
    }
    __syncthreads();

    int idx = ((bh << 6) + pos) * 64 + (t >> 6) * 8;
    {
        int cg2 = t >> 6;
        float4 x0 = *(const float4*)&xio[idx];
        float4 x1 = *(const float4*)&xio[idx + 4];
        float* tp = &ts[pos * 65 + cg2 * 8];
        tp[0] += x0.x; tp[1] += x0.y; tp[2] += x0.z; tp[3] += x0.w;
        tp[4] += x1.x; tp[5] += x1.y; tp[6] += x1.z; tp[7] += x1.w;
    }
    __syncthreads();

    // ln2 parallel -> ys bf16
    {
        int tok = t >> 3, j8 = (t & 7) * 8;
        float v[8];
        float ls = 0.f, lq = 0.f;
#pragma unroll
        for (int ci = 0; ci < 8; ++ci) {
            v[ci] = ts[tok * 65 + j8 + ci];
            ls += v[ci]; lq += v[ci] * v[ci];
        }
#pragma unroll
        for (int off = 1; off < 8; off <<= 1) {
            ls += __shfl_xor(ls, off, 64);
            lq += __shfl_xor(lq, off, 64);
        }
        float mu = ls * (1.f / 64.f);
        float vr = lq * (1.f / 64.f) - mu * mu;
        float rs = rsqrtf(fmaxf(vr, 0.f) + 1e-5f);
        float wv[8], bv[8], yv[8];
        ldp8(ln2w, j8, md, wv);
        ldp8(ln2b, j8, md, bv);
#pragma unroll
        for (int ci = 0; ci < 8; ++ci) yv[ci] = (v[ci] - mu) * rs * wv[ci] + bv[ci];
        *(uint4*)&ys[tok * 72 + j8] = pk_bf8(yv);
    }
    __syncthreads();

    // MLP1 + GELU -> hs
    {
        f32x4 ma0 = (f32x4){0.f,0.f,0.f,0.f}, ma1 = (f32x4){0.f,0.f,0.f,0.f};
#pragma unroll
        for (int kt = 0; kt < 2; ++kt) {
            bf16x8 av = *(const bf16x8*)&ys[(mt * 16 + nl) * 72 + kt * 32 + qd * 8];
            bf16x8 b0 = *(const bf16x8*)(ff1s + o0 * 64 + kt * 32 + qd * 8);
            bf16x8 b1 = *(const bf16x8*)(ff1s + o1 * 64 + kt * 32 + qd * 8);
            ma0 = __builtin_amdgcn_mfma_f32_16x16x32_bf16(av, b0, ma0, 0, 0, 0);
            ma1 = __builtin_amdgcn_mfma_f32_16x16x32_bf16(av, b1, ma1, 0, 0, 0);
        }
        float f1b0 = ldp(ff1b, o0, md), f1b1 = ldp(ff1b, o1, md);
#pragma unroll
        for (int r2 = 0; r2 < 4; ++r2) {
            int m = mt * 16 + qd * 4 + r2;
            float v0 = ma0[r2] + f1b0;
            float v1 = ma1[r2] + f1b1;
            hs[m * 72 + o0] = (short)f2bfu(0.5f * v0 * (1.f + erff(v0 * 0.70710678118654752f)));
            hs[m * 72 + o1] = (short)f2bfu(0.5f * v1 * (1.f + erff(v1 * 0.70710678118654752f)));
        }
    }
    __syncthreads();

    // MLP2 + residual into ts
    {
        f32x4 fa0 = (f32x4){0.f,0.f,0.f,0.f}, fa1 = (f32x4){0.f,0.f,0.f,0.f};
#pragma unroll
        for (int kt = 0; kt < 2; ++kt) {
            bf16x8 av = *(const bf16x8*)&hs[(mt * 16 + nl) * 72 + kt * 32 + qd * 8];
            bf16x8 b0 = *(const bf16x8*)(ff2s + o0 * 64 + kt * 32 + qd * 8);
            bf16x8 b1 = *(const bf16x8*)(ff2s + o1 * 64 + kt * 32 + qd * 8);
            fa0 = __builtin_amdgcn_mfma_f32_16x16x32_bf16(av, b0, fa0, 0, 0, 0);
            fa1 = __builtin_amdgcn_mfma_f32_16x16x32_bf16(av, b1, fa1, 0, 0, 0);
        }
        float f2b0 = ldp(ff2b, o0, md), f2b1 = ldp(ff2b, o1, md);
#pragma unroll
        for (int r2 = 0; r2 < 4; ++r2) {
            int m = mt * 16 + qd * 4 + r2;
            ts[m * 65 + o0] += fa0[r2] + f2b0;
            ts[m * 65 + o1] += fa1[r2] + f2b1;
        }
    }
    __syncthreads();

    {
        int cg2 = t >> 6;
        float fv[8];
#pragma unroll
        for (int ci = 0; ci < 8; ++ci) {
            float v = ts[pos * 65 + cg2 * 8 + ci];
            if (cg2 == 0 && ci == 0) v = c0buf[(bh << 6) + pos];
            fv[ci] = finz(v);
        }
        *(float4*)&xio[idx]     = make_float4(fv[0], fv[1], fv[2], fv[3]);
        *(float4*)&xio[idx + 4] = make_float4(fv[4], fv[5], fv[6], fv[7]);
        if (write_out) {
            if (md) {
                *(float4*)&((float*)dout)[idx]     = make_float4(fv[0], fv[1], fv[2], fv[3]);
                *(float4*)&((float*)dout)[idx + 4] = make_float4(fv[4], fv[5], fv[6], fv[7]);
            } else {
                *(uint4*)&((bf16*)dout)[idx] = pk_bf8(fv);
            }
        }
    }
}

// ---------------- launch ----------------

extern "C" void kernel_launch(void* const* d_in, const int* in_sizes, int n_in,
                              void* d_out, int out_size, void* d_ws, size_t ws_size,
                              hipStream_t stream) {
    (void)in_sizes; (void)n_in; (void)out_size; (void)ws_size;
    const void* x     = d_in[0];
    const void* masks = d_in[1];
    const void* p0w   = d_in[2];
    const void* p0b   = d_in[3];
    const void* p1w   = d_in[4];
    const void* p1b   = d_in[5];
    const void* fc0w  = d_in[6];
    const void* fc0b  = d_in[7];
    const void* fc1w  = d_in[8];
    const void* n0w   = d_in[9];
    const void* n0b   = d_in[10];
    const void* ln1w  = d_in[11];
    const void* ln1b  = d_in[12];
    const void* qkvw  = d_in[13];
    const void* outw  = d_in[14];
    const void* outb  = d_in[15];
    const void* ln2w  = d_in[16];
    const void* ln2b  = d_in[17];
    const void* ff1w  = d_in[18];
    const void* ff1b  = d_in[19];
    const void* ff2w  = d_in[20];
    const void* ff2b  = d_in[21];

    char* wsb = (char*)d_ws;
    float* xst      = (float*)(wsb + 0);           //  8,388,608 B fp32 state
    bf16*  qkvb     = (bf16*) (wsb + 8388608);     // 12,582,912 B (aliases hd)
    bf16*  hd       = (bf16*) (wsb + 8388608);
    float* c0buf    = (float*)(wsb + 20971520);    //    131,072 B
    short* bt1      = (short*)(wsb + 21102592);    //    147,456 B
    short* packbase = (short*)(wsb + 21250048);    //    114,688 B
    float* accv     = (float*)(wsb + 21364736);    //        384 B
    int*   mflags   = (int*)  (wsb + 21365120);    //         16 B

    const short* fc0s = packbase;
    const short* fc1s = packbase + 24576;
    const short* qkvs = packbase + 32768;
    const short* outs = packbase + 45056;
    const short* ff1s = packbase + 49152;
    const short* ff2s = packbase + 53248;

    k_detect<<<1, 256, 0, stream>>>((const uint4*)masks, (const uint4*)x, mflags, accv);
    k_cast<<<1024, 256, 0, stream>>>(x, xst, mflags, 262144);
    k_pack_bt1<<<288, 256, 0, stream>>>(p0w, p1w, bt1, mflags);
    k_pack_all<<<224, 256, 0, stream>>>(fc0w, fc1w, qkvw, outw, ff1w, ff2w,
                                        packbase, mflags);

    for (int s = 0; s < NSTEP; ++s) {
        k_perceive<<<512, 512, 0, stream>>>(xst, bt1, fc0s, p0b, p1b, fc0b,
                                            mflags, hd, accv, s);
        k_update_qkv<<<512, 512, 0, stream>>>(xst, hd, fc1s, n0w, n0b, masks,
                                              mflags, accv, c0buf, qkvs,
                                              ln1w, ln1b, qkvb, s);
        k_attn_ff<<<512, 512, 0, stream>>>(qkvb, xst, c0buf, outs, ff1s, ff2s,
                                           outb, ln2w, ln2b, ff1b, ff2b, mflags,
                                           d_out, (s == NSTEP - 1) ? 1 : 0);
    }
}